// Round 10
// baseline (356.559 us; speedup 1.0000x reference)
//
#include <hip/hip_runtime.h>
#include <cmath>

typedef unsigned short u16;
typedef __bf16 bf16x8 __attribute__((ext_vector_type(8)));
typedef float f32x4 __attribute__((ext_vector_type(4)));
typedef float float4v __attribute__((ext_vector_type(4)));
typedef u16 ushort4v __attribute__((ext_vector_type(4)));
typedef u16 ushort8v __attribute__((ext_vector_type(8)));

#define DIMC 768
#define NP 196
#define MTOT 6272         // 32*196
#define HIDC 3072
#define LAMC 3.5f

__device__ const float C14d[14] = {
  1.0f, 0.9009688679024191f, 0.6234898018587336f, 0.22252093395631445f,
  -0.22252093395631445f, -0.6234898018587336f, -0.9009688679024191f, -1.0f,
  -0.9009688679024191f, -0.6234898018587336f, -0.22252093395631445f,
  0.22252093395631445f, 0.6234898018587336f, 0.9009688679024191f
};
__device__ const float S14d[14] = {
  0.0f, 0.43388373911755823f, 0.7818314824680298f, 0.9749279121818236f,
  0.9749279121818236f, 0.7818314824680298f, 0.43388373911755823f, 0.0f,
  -0.43388373911755823f, -0.7818314824680298f, -0.9749279121818236f,
  -0.9749279121818236f, -0.7818314824680298f, -0.43388373911755823f
};

__device__ __forceinline__ u16 f2bf(float f) {
  unsigned u = __builtin_bit_cast(unsigned, f);
  unsigned r = u + 0x7FFFu + ((u >> 16) & 1u);
  return (u16)(r >> 16);
}

typedef const __attribute__((address_space(1))) u16* gas_p;
typedef __attribute__((address_space(3))) u16* las_p;
__device__ __forceinline__ void gl16(const u16* g, u16* l) {
  __builtin_amdgcn_global_load_lds((gas_p)g, (las_p)l, 16, 0, 0);
}

// ---------------- fused prep: initfg + weight cvt + x cvt (1 dispatch) ------
__global__ __launch_bounds__(256) void prep_k(
    const float* __restrict__ v_w, const float* __restrict__ fc2w,
    const float* __restrict__ x,
    u16* __restrict__ vwbf, u16* __restrict__ fc2bf, u16* __restrict__ xbf,
    u16* __restrict__ Ff, u16* __restrict__ Gf) {
  const int bid = blockIdx.x, t = threadIdx.x;
  if (bid < 378) {                           // initfg
    int idx = bid * 256 + t;
    if (idx < 50176) {                       // Ff: 14*7*64*8
      int j = idx & 7, lane = (idx >> 3) & 63;
      int mk = idx >> 9, k0 = mk % 7, m0 = mk / 7;
      int s = m0 * 16 + (lane & 15);
      int q = k0 * 32 + (lane >> 4) * 8 + j;
      float v = 0.f;
      if (q < 196) {
        int kr = s >> 4, f = (s >> 1) & 7, r = q / 14, c = q % 14;
        int th = (kr * r + f * c) % 14;
        v = (s & 1) ? -S14d[th] : C14d[th];
      }
      Ff[idx] = f2bf(v);
    } else {                                 // Gf: 13*7*64*8
      int t2 = idx - 50176;
      int j = t2 & 7, lane = (t2 >> 3) & 63;
      int pk = t2 >> 9, k0 = pk % 7, p0 = pk / 7;
      int p = p0 * 16 + (lane & 15);
      int s = k0 * 32 + (lane >> 4) * 8 + j;
      float v = 0.f;
      if (p < 196) {
        int kr = s >> 4, f = (s >> 1) & 7, r = p / 14, c = p % 14;
        int th = (kr * r + f * c) % 14;
        float w = (f == 0 || f == 7) ? 1.f : 2.f;
        v = (w * (1.f / 196.f)) * ((s & 1) ? -S14d[th] : C14d[th]);
      }
      Gf[t2] = f2bf(v);
    }
  } else if (bid < 3258) {                   // v_w + fc2w -> bf16
    int idx = (bid - 378) * 256 + t;
    const float* s; u16* d; int base;
    if (idx < 147456) { s = v_w; d = vwbf; base = 0; }
    else              { s = fc2w; d = fc2bf; base = 147456; }
    int i4 = (idx - base) * 4;
    float4v v = *(const float4v*)(s + i4);
    ushort4v o;
#pragma unroll
    for (int j = 0; j < 4; ++j) o[j] = f2bf(v[j]);
    *(ushort4v*)(d + i4) = o;
  } else {                                   // x -> bf16
    int idx = (bid - 3258) * 256 + t;
    int i4 = idx * 4;
    float4v v = *(const float4v*)(x + i4);
    ushort4v o;
#pragma unroll
    for (int j = 0; j < 4; ++j) o[j] = f2bf(v[j]);
    *(ushort4v*)(xbf + i4) = o;
  }
}

// ---------------- 128x128 bf16 MFMA GEMM (R3 body + XCD decode) ----------
// EPI 0: f32x4 transpose-write vxt[(b*768+n)*196+np]; EPI 1: +bias+res f32;
// EPI 2: bf16 gelu(acc+bias)
template<int EPI>
__global__ __launch_bounds__(256) void gemm_k(
    const u16* __restrict__ A, const u16* __restrict__ Bw,
    const float* __restrict__ bias, const float* __restrict__ res,
    void* __restrict__ Cp, int Nr, int Kr, int ld, int NB) {
  __shared__ __attribute__((aligned(16))) u16 As[128 * 32];
  __shared__ __attribute__((aligned(16))) u16 Bs[128 * 32];
  const int t = threadIdx.x;
  const int wid = t >> 6, lane = t & 63;

  const int bid = blockIdx.x;
  const int xcd = bid & 7, j = bid >> 3;
  const int bmi = xcd + 8 * (j / NB);
  if (bmi >= 49) return;
  const int bn = (j % NB) * 128, bm = bmi * 128;

  const int wm = (wid >> 1) * 64, wn = (wid & 1) * 64;
  const int l15 = lane & 15, l4 = lane >> 4;
  const int srow = lane >> 2, scol = (lane & 3) * 8;

  f32x4 acc[4][4];
#pragma unroll
  for (int a = 0; a < 4; ++a)
#pragma unroll
    for (int b2 = 0; b2 < 4; ++b2) acc[a][b2] = (f32x4){0.f, 0.f, 0.f, 0.f};

  const u16* gA0 = A + (size_t)(bm + wid * 16 + srow) * ld + scol;
  const u16* gB0 = Bw + (size_t)(bn + wid * 16 + srow) * ld + scol;
  u16* lA = As + wid * 512;
  u16* lB = Bs + wid * 512;

  for (int k0 = 0; k0 < Kr; k0 += 32) {
    gl16(gA0 + k0, lA);
    gl16(gA0 + (size_t)64 * ld + k0, lA + 2048);
    gl16(gB0 + k0, lB);
    gl16(gB0 + (size_t)64 * ld + k0, lB + 2048);
    __syncthreads();

    bf16x8 af[4], bfv[4];
#pragma unroll
    for (int mb = 0; mb < 4; ++mb)
      af[mb] = *(const bf16x8*)&As[(wm + mb * 16 + l15) * 32 + l4 * 8];
#pragma unroll
    for (int nb = 0; nb < 4; ++nb)
      bfv[nb] = *(const bf16x8*)&Bs[(wn + nb * 16 + l15) * 32 + l4 * 8];
#pragma unroll
    for (int mb = 0; mb < 4; ++mb)
#pragma unroll
      for (int nb = 0; nb < 4; ++nb)
        acc[mb][nb] = __builtin_amdgcn_mfma_f32_16x16x32_bf16(af[mb], bfv[nb], acc[mb][nb], 0, 0, 0);
    __syncthreads();
  }

#pragma unroll
  for (int mb = 0; mb < 4; ++mb) {
#pragma unroll
    for (int nb = 0; nb < 4; ++nb) {
      int n = bn + wn + nb * 16 + l15;
      if (EPI == 0) {
        int m0 = bm + wm + mb * 16 + l4 * 4;
        int bb = m0 / 196, np0 = m0 - bb * 196;
        *(float4v*)&((float*)Cp)[((size_t)bb * DIMC + n) * 196 + np0] =
            (float4v){acc[mb][nb][0], acc[mb][nb][1], acc[mb][nb][2], acc[mb][nb][3]};
      } else {
#pragma unroll
        for (int r = 0; r < 4; ++r) {
          int m = bm + wm + mb * 16 + l4 * 4 + r;
          float v = acc[mb][nb][r];
          if (EPI == 1) {
            ((float*)Cp)[(size_t)m * Nr + n] = v + bias[n] + res[(size_t)m * Nr + n];
          } else {
            float vb = v + bias[n];
            float ge = 0.5f * vb * (1.f + erff(vb * 0.70710678118654752f));
            ((u16*)Cp)[(size_t)m * Nr + n] = f2bf(ge);
          }
        }
      }
    }
  }
}

// ---------------- MFMA screen: max_i max_p |u_i| per tile, flag > 3.4 ----------
__global__ __launch_bounds__(64) void checkmfma_k(
    const float* __restrict__ vxt, const float* __restrict__ kern,
    const u16* __restrict__ Ff, const u16* __restrict__ Gf,
    int* __restrict__ cnt, int* __restrict__ wl) {
  __shared__ float xf[16 * 228];
  const int lane = threadIdx.x;
  const int wgb = blockIdx.x;
  const int g = wgb >> 1, bhalf = wgb & 1;
  const int tl = lane & 15, h = lane >> 4;
  const float* xbase = vxt + ((size_t)(bhalf * 16 + tl) * DIMC + g) * 196;

  bf16x8 Bx[7];
#pragma unroll
  for (int k0 = 0; k0 < 7; ++k0) {
    int q0 = k0 * 32 + h * 8;
    ushort8v tv;
    if (k0 < 6) {
      float4v f0 = *(const float4v*)(xbase + q0);
      float4v f1 = *(const float4v*)(xbase + q0 + 4);
#pragma unroll
      for (int j = 0; j < 4; ++j) { tv[j] = f2bf(f0[j]); tv[j + 4] = f2bf(f1[j]); }
    } else {
#pragma unroll
      for (int j = 0; j < 8; ++j) {
        int q = q0 + j;
        tv[j] = (q < 196) ? f2bf(xbase[q]) : (u16)0;
      }
    }
    Bx[k0] = __builtin_bit_cast(bf16x8, tv);
  }

  for (int m0 = 0; m0 < 14; ++m0) {
    f32x4 acc = (f32x4){0.f, 0.f, 0.f, 0.f};
#pragma unroll
    for (int k0 = 0; k0 < 7; ++k0) {
      bf16x8 Af = __builtin_bit_cast(bf16x8,
          *(const ushort8v*)(Ff + ((size_t)(m0 * 7 + k0) * 64 + lane) * 8));
      acc = __builtin_amdgcn_mfma_f32_16x16x32_bf16(Af, Bx[k0], acc, 0, 0, 0);
    }
    *(f32x4*)&xf[tl * 228 + m0 * 16 + h * 4] = acc;
  }

  bf16x8 By[5][7];
#pragma unroll
  for (int i = 0; i < 5; ++i) {
    const float* kb = kern + ((size_t)g * 5 + i) * 224;
#pragma unroll
    for (int k0 = 0; k0 < 7; ++k0) {
      f32x4 x0 = *(const f32x4*)&xf[tl * 228 + k0 * 32 + h * 8];
      f32x4 x1 = *(const f32x4*)&xf[tl * 228 + k0 * 32 + h * 8 + 4];
      int mb = k0 * 16 + h * 4;
      float2 ka = *(const float2*)(kb + (mb + 0) * 2);
      float2 kc = *(const float2*)(kb + (mb + 1) * 2);
      float2 ke = *(const float2*)(kb + (mb + 2) * 2);
      float2 kg = *(const float2*)(kb + (mb + 3) * 2);
      ushort8v tv;
      tv[0] = f2bf(ka.x * x0[0] - ka.y * x0[1]);
      tv[1] = f2bf(ka.x * x0[1] + ka.y * x0[0]);
      tv[2] = f2bf(kc.x * x0[2] - kc.y * x0[3]);
      tv[3] = f2bf(kc.x * x0[3] + kc.y * x0[2]);
      tv[4] = f2bf(ke.x * x1[0] - ke.y * x1[1]);
      tv[5] = f2bf(ke.x * x1[1] + ke.y * x1[0]);
      tv[6] = f2bf(kg.x * x1[2] - kg.y * x1[3]);
      tv[7] = f2bf(kg.x * x1[3] + kg.y * x1[2]);
      By[i][k0] = __builtin_bit_cast(bf16x8, tv);
    }
  }

  float vmax = 0.f;
  for (int p0 = 0; p0 < 13; ++p0) {
    f32x4 a0 = (f32x4){0.f, 0.f, 0.f, 0.f};
    f32x4 a1 = a0, a2 = a0, a3 = a0, a4 = a0;
#pragma unroll
    for (int k0 = 0; k0 < 7; ++k0) {
      bf16x8 Ag = __builtin_bit_cast(bf16x8,
          *(const ushort8v*)(Gf + ((size_t)(p0 * 7 + k0) * 64 + lane) * 8));
      a0 = __builtin_amdgcn_mfma_f32_16x16x32_bf16(Ag, By[0][k0], a0, 0, 0, 0);
      a1 = __builtin_amdgcn_mfma_f32_16x16x32_bf16(Ag, By[1][k0], a1, 0, 0, 0);
      a2 = __builtin_amdgcn_mfma_f32_16x16x32_bf16(Ag, By[2][k0], a2, 0, 0, 0);
      a3 = __builtin_amdgcn_mfma_f32_16x16x32_bf16(Ag, By[3][k0], a3, 0, 0, 0);
      a4 = __builtin_amdgcn_mfma_f32_16x16x32_bf16(Ag, By[4][k0], a4, 0, 0, 0);
    }
#pragma unroll
    for (int r = 0; r < 4; ++r) {
      vmax = fmaxf(vmax, fabsf(a0[r]));
      vmax = fmaxf(vmax, fabsf(a1[r]));
      vmax = fmaxf(vmax, fabsf(a2[r]));
      vmax = fmaxf(vmax, fabsf(a3[r]));
      vmax = fmaxf(vmax, fabsf(a4[r]));
    }
  }
  vmax = fmaxf(vmax, __shfl_xor(vmax, 16));
  vmax = fmaxf(vmax, __shfl_xor(vmax, 32));
  if (lane < 16 && vmax > (LAMC - 0.1f)) {
    int idx = atomicAdd(cnt, 1);
    wl[idx] = g * 32 + bhalf * 16 + lane;
  }
}

// ---------------- full ISTA for flagged tiles + fused tile sums -------------
__global__ __launch_bounds__(64) void slow_k(
    const float* __restrict__ vxt, const float* __restrict__ kern,
    const float* __restrict__ kern2, const float* __restrict__ Lbuf,
    const int* __restrict__ cnt, const int* __restrict__ wl,
    float* __restrict__ outp,
    float* __restrict__ tsum, float* __restrict__ tsq,
    unsigned* __restrict__ maskg, unsigned* __restrict__ bmask) {
  const int ntile = *cnt;
  if ((int)blockIdx.x >= ntile) return;
  const int t = threadIdx.x;
  __shared__ float TC[196], TSn[196];
  __shared__ float xs[196];
  __shared__ float t1R[112], t1I[112];
  __shared__ float t2R[112], t2I[112];
  __shared__ float zr[112], zi[112];
  __shared__ float kR[5][112], kI[5][112];
  __shared__ float uu[5][196];
  __shared__ float ss[5][196];
  __shared__ float k2R[112], k2I[112];

  for (int i = t; i < 196; i += 64) {
    int a = i / 14, c = i - (i / 14) * 14;
    int m = (a * c) % 14;
    TC[i] = C14d[m]; TSn[i] = S14d[m];
  }

  auto rowsFwd = [&](const float* xsrc) {
    for (int i = t; i < 112; i += 64) {
      int r = i >> 3, f = i & 7;
      const float* xp = xsrc + r * 14;
      const float* tc = &TC[f * 14]; const float* tsn = &TSn[f * 14];
      float ar = 0.f, ai = 0.f;
#pragma unroll
      for (int c = 0; c < 14; ++c) { float xv = xp[c]; ar += xv * tc[c]; ai -= xv * tsn[c]; }
      t1R[i] = ar; t1I[i] = ai;
    }
    __syncthreads();
  };
  auto colsFwd = [&](float* oR, float* oI) {
    for (int i = t; i < 112; i += 64) {
      int kr = i >> 3, f = i & 7;
      const float* tc = &TC[kr * 14]; const float* tsn = &TSn[kr * 14];
      float br = 0.f, bi = 0.f;
#pragma unroll
      for (int r = 0; r < 14; ++r) {
        float xr = t1R[r * 8 + f], xi = t1I[r * 8 + f];
        br += tc[r] * xr + tsn[r] * xi;
        bi += tc[r] * xi - tsn[r] * xr;
      }
      oR[i] = br; oI[i] = bi;
    }
    __syncthreads();
  };
  auto colsInv = [&]() {
    for (int i = t; i < 112; i += 64) {
      int r = i >> 3, f = i & 7;
      const float* tc = &TC[r * 14]; const float* tsn = &TSn[r * 14];
      float br = 0.f, bi = 0.f;
#pragma unroll
      for (int kr = 0; kr < 14; ++kr) {
        float xr = t1R[kr * 8 + f], xi = t1I[kr * 8 + f];
        br += tc[kr] * xr - tsn[kr] * xi;
        bi += tc[kr] * xi + tsn[kr] * xr;
      }
      t2R[i] = br; t2I[i] = bi;
    }
    __syncthreads();
  };
  auto rowVal = [&](int r, int c) -> float {
    const float* pR = &t2R[r * 8]; const float* pI = &t2I[r * 8];
    float v = pR[0] + ((c & 1) ? -pR[7] : pR[7]);
    float s2 = 0.f;
#pragma unroll
    for (int f = 1; f < 7; ++f) s2 += pR[f] * TC[f * 14 + c] - pI[f] * TSn[f * 14 + c];
    return (v + 2.f * s2) * (1.0f / 196.0f);
  };

  for (int widx = blockIdx.x; widx < ntile; widx += gridDim.x) {
    const int tile = wl[widx];
    const int g = tile >> 5, b = tile & 31;
    __syncthreads();
    for (int i = t; i < 560; i += 64) {
      int ii = i / 112, p = i - ii * 112;
      const float* kp = kern + ((size_t)g * 5 + ii) * 224 + p * 2;
      kR[ii][p] = kp[0]; kI[ii][p] = kp[1];
    }
    for (int i = t; i < 196; i += 64) xs[i] = vxt[((size_t)b * DIMC + g) * 196 + i];
    for (int i = t; i < 112; i += 64) {
      k2R[i] = kern2[(size_t)g * 224 + i * 2];
      k2I[i] = kern2[(size_t)g * 224 + i * 2 + 1];
    }
    __syncthreads();

    rowsFwd(xs);
    colsFwd(zr, zi);
    for (int ii = 0; ii < 5; ++ii) {
      for (int i = t; i < 112; i += 64) {
        float a = kR[ii][i], b2 = kI[ii][i];
        t1R[i] = a * zr[i] - b2 * zi[i];
        t1I[i] = a * zi[i] + b2 * zr[i];
      }
      __syncthreads();
      colsInv();
      for (int i = t; i < 196; i += 64) uu[ii][i] = rowVal(i / 14, i - (i / 14) * 14);
      __syncthreads();
    }

    const float invL = 1.0f / Lbuf[g];
    const float thr = LAMC * invL;
    {
      float* up = &uu[0][0];
      float* sp = &ss[0][0];
      for (int i = t; i < 980; i += 64) {
        float v = up[i];
        float a = fabsf(v) - LAMC;
        sp[i] = a > 0.f ? copysignf(a, v) : 0.f;
      }
    }
    __syncthreads();

    for (int iter = 0; iter < 4; ++iter) {
      for (int i = t; i < 112; i += 64) { zr[i] = 0.f; zi[i] = 0.f; }
      __syncthreads();
      for (int ii = 0; ii < 5; ++ii) {
        rowsFwd(&ss[ii][0]);
        colsFwd(t2R, t2I);
        for (int i = t; i < 112; i += 64) {
          float a = kR[ii][i], b2 = kI[ii][i];
          zr[i] += a * t2R[i] + b2 * t2I[i];
          zi[i] += a * t2I[i] - b2 * t2R[i];
        }
        __syncthreads();
      }
      if (iter == 3) break;
      for (int ii = 0; ii < 5; ++ii) {
        for (int i = t; i < 112; i += 64) {
          float a = kR[ii][i], b2 = kI[ii][i];
          t1R[i] = a * zr[i] - b2 * zi[i];
          t1I[i] = a * zi[i] + b2 * zr[i];
        }
        __syncthreads();
        colsInv();
        for (int i = t; i < 196; i += 64) {
          float v = rowVal(i / 14, i - (i / 14) * 14);
          float sv = ss[ii][i] - (v - uu[ii][i]) * invL;
          float aa = fabsf(sv) - thr;
          ss[ii][i] = aa > 0.f ? copysignf(aa, sv) : 0.f;
        }
        __syncthreads();
      }
    }

    if (t < 28) {
      int kr = t >> 1, f = (t & 1) * 7;
      int d = kr * 8 + f;
      int srci = ((14 - kr) % 14) * 8 + f;
      float pr = 0.5f * (zr[d] + zr[srci]);
      float pi = 0.5f * (zi[d] - zi[srci]);
      zr[d] = pr; zi[d] = pi;
    }
    __syncthreads();
    for (int i = t; i < 112; i += 64) {
      float a = k2R[i], b2 = k2I[i];
      t1R[i] = a * zr[i] - b2 * zi[i];
      t1I[i] = a * zi[i] + b2 * zr[i];
    }
    __syncthreads();
    colsInv();
    float sacc = 0.f, qacc = 0.f;
    for (int i = t; i < 196; i += 64) {
      float v = rowVal(i / 14, i - (i / 14) * 14);
      outp[((size_t)(b * 196 + i)) * DIMC + g] = v;
      sacc += v; qacc += v * v;
    }
#pragma unroll
    for (int off = 32; off; off >>= 1) {
      sacc += __shfl_xor(sacc, off);
      qacc += __shfl_xor(qacc, off);
    }
    if (t == 0) {
      tsum[tile] = sacc; tsq[tile] = qacc;
      atomicOr(&maskg[g], 1u << b);
      atomicOr(bmask, 1u << b);
    }
  }
}

// ---------------- BN1 finalize + c0 in one dispatch (3 blocks) --------------
__global__ __launch_bounds__(256) void stats1c0_k(
    const float* __restrict__ tsum, const float* __restrict__ tsq,
    const unsigned* __restrict__ maskg,
    const float* __restrict__ gam, const float* __restrict__ bet,
    const float* __restrict__ projw, const float* __restrict__ pb,
    float* __restrict__ sc1, float* __restrict__ c0) {
  __shared__ float sh1s[768];
  const int t = threadIdx.x;
  for (int c = t; c < DIMC; c += 256) {
    unsigned mask = maskg[c];
    float S = 0.f, Q = 0.f;
    if (mask) {
      for (int b = 0; b < 32; ++b)
        if ((mask >> b) & 1) { S += tsum[c * 32 + b]; Q += tsq[c * 32 + b]; }
    }
    float m = S * (1.0f / 6272.0f);
    float v = fmaxf(Q * (1.0f / 6272.0f) - m * m, 0.f);
    float rs = rsqrtf(v + 1e-5f);
    float sc = gam[c] * rs;
    sh1s[c] = bet[c] - m * sc;
    if (blockIdx.x == 0) sc1[c] = sc;
  }
  __syncthreads();
  int n = blockIdx.x * 256 + t;
  const float* row = projw + (size_t)n * DIMC;
  float s = 0.f;
  for (int g = 0; g < DIMC; g += 4) {
    float4v r = *(const float4v*)(row + g);
    s += r[0] * sh1s[g] + r[1] * sh1s[g + 1] + r[2] * sh1s[g + 2] + r[3] * sh1s[g + 3];
  }
  c0[n] = s + pb[n];
}

// ---------------- fused: new2 = x + c0 + sparse-corr; emit f32+bf16; BN2 partials
// grid dim3(28, 32): block = 7 rows of batch b. Deterministic (ascending g).
__global__ __launch_bounds__(256) void bnb_k(
    const float* __restrict__ x, const float* __restrict__ c0,
    const float* __restrict__ sc1, const unsigned* __restrict__ maskg,
    const unsigned* __restrict__ bmask, const float* __restrict__ newm,
    const float* __restrict__ projw,
    float* __restrict__ new2, u16* __restrict__ n2bf,
    float* __restrict__ part) {
  const int jb = blockIdx.x, b = blockIdx.y, t = threadIdx.x;
  __shared__ unsigned gm[24];
  __shared__ float c0s[768];
  const bool hasb = ((*bmask >> b) & 1u) != 0u;
  if (t < 24) {
    unsigned w = 0;
    if (hasb)
      for (int j2 = 0; j2 < 32; ++j2) w |= ((maskg[t * 32 + j2] >> b) & 1u) << j2;
    gm[t] = w;
  }
  for (int c = t; c < 768; c += 256) c0s[c] = c0[c];
  __syncthreads();

  float S0 = 0, S1 = 0, S2 = 0, Q0 = 0, Q1 = 0, Q2 = 0;
  for (int mr = 0; mr < 7; ++mr) {
    size_t row = ((size_t)b * 196 + jb * 7 + mr) * DIMC;
#pragma unroll
    for (int j2 = 0; j2 < 3; ++j2) {
      int n = t + j2 * 256;
      float v = x[row + n] + c0s[n];
      if (hasb) {
        for (int w = 0; w < 24; ++w) {
          unsigned bits = gm[w];
          while (bits) {
            int g = w * 32 + __builtin_ctz(bits);
            bits &= bits - 1;
            v += sc1[g] * newm[row + g] * projw[(size_t)n * DIMC + g];
          }
        }
      }
      new2[row + n] = v;
      n2bf[row + n] = f2bf(v);
      if (j2 == 0) { S0 += v; Q0 += v * v; }
      else if (j2 == 1) { S1 += v; Q1 += v * v; }
      else { S2 += v; Q2 += v * v; }
    }
  }
  float* p = part + (size_t)(b * 28 + jb) * 1536;
  p[t] = S0; p[t + 256] = S1; p[t + 512] = S2;
  p[768 + t] = Q0; p[768 + 256 + t] = Q1; p[768 + 512 + t] = Q2;
}

// ---------------- BN2 finalize (3 blocks; reduces 896 partials) -------------
__global__ __launch_bounds__(256) void stats2fin_k(const float* __restrict__ part,
    const float* __restrict__ gam, const float* __restrict__ bet,
    float* __restrict__ scale, float* __restrict__ shift) {
  int c = blockIdx.x * 256 + threadIdx.x;
  float S = 0.f, Q = 0.f;
  for (int bid = 0; bid < 896; ++bid) {
    S += part[(size_t)bid * 1536 + c];
    Q += part[(size_t)bid * 1536 + 768 + c];
  }
  float m = S * (1.0f / 6272.0f);
  float v = fmaxf(Q * (1.0f / 6272.0f) - m * m, 0.f);
  float rs = rsqrtf(v + 1e-5f);
  float sc = gam[c] * rs;
  scale[c] = sc;
  shift[c] = bet[c] - m * sc;
}

// ---------------- fold BN2 into fc1: d0 + fc1s (one dispatch, 2316 blocks) ---
__global__ __launch_bounds__(256) void foldfc1_k(const float* __restrict__ fc1w,
    const float* __restrict__ fc1b, const float* __restrict__ sc2,
    const float* __restrict__ sh2, u16* __restrict__ fc1s,
    float* __restrict__ d0) {
  const int bid = blockIdx.x, t = threadIdx.x;
  if (bid < 12) {
    int n = bid * 256 + t;
    const float* row = fc1w + (size_t)n * DIMC;
    float s = 0.f;
    for (int k = 0; k < DIMC; k += 4) {
      float4v r = *(const float4v*)(row + k);
      float4v h = *(const float4v*)(sh2 + k);
      s += r[0] * h[0] + r[1] * h[1] + r[2] * h[2] + r[3] * h[3];
    }
    d0[n] = s + fc1b[n];
  } else {
    int idx = (bid - 12) * 256 + t;
    int i4 = idx * 4;
    int k = i4 % DIMC;
    float4v v = *(const float4v*)(fc1w + i4);
    float4v s = *(const float4v*)(sc2 + k);
    v = v * s;
    ushort4v o;
#pragma unroll
    for (int j = 0; j < 4; ++j) o[j] = f2bf(v[j]);
    *(ushort4v*)(fc1s + i4) = o;
  }
}

// ---------------- launch ----------------
extern "C" void kernel_launch(void* const* d_in, const int* in_sizes, int n_in,
                              void* d_out, int out_size, void* d_ws, size_t ws_size,
                              hipStream_t stream) {
  (void)in_sizes; (void)n_in; (void)out_size;
  const float* x      = (const float*)d_in[0];
  const float* v_w    = (const float*)d_in[1];
  const float* proj_w = (const float*)d_in[2];
  const float* proj_b = (const float*)d_in[3];
  const float* kern   = (const float*)d_in[4];
  const float* kern2  = (const float*)d_in[5];
  const float* n1g    = (const float*)d_in[6];
  const float* n1b    = (const float*)d_in[7];
  const float* n2g    = (const float*)d_in[8];
  const float* n2b    = (const float*)d_in[9];
  const float* fc1w   = (const float*)d_in[10];
  const float* fc1b   = (const float*)d_in[11];
  const float* fc2w   = (const float*)d_in[12];
  const float* fc2b   = (const float*)d_in[13];
  const float* Lb     = (const float*)d_in[14];
  float* out = (float*)d_out;

  char* ws = (char*)d_ws;
  size_t o = 0;
  auto alloc = [&](size_t bytes) { size_t r = o; o += (bytes + 255) & ~(size_t)255; return r; };
  u16*   vwbf   = (u16*)(ws + alloc(589824 * 2));
  u16*   fc2bf  = (u16*)(ws + alloc(2359296 * 2));
  u16*   fc1s   = (u16*)(ws + alloc(2359296 * 2));
  u16*   Ffb    = (u16*)(ws + alloc(50176 * 2));
  u16*   Gfb    = (u16*)(ws + alloc(46592 * 2));
  float* sc1    = (float*)(ws + alloc(768 * 4));
  float* sc2    = (float*)(ws + alloc(768 * 4));
  float* sh2    = (float*)(ws + alloc(768 * 4));
  float* c0     = (float*)(ws + alloc(768 * 4));
  float* d0     = (float*)(ws + alloc(3072 * 4));
  float* part   = (float*)(ws + alloc((size_t)896 * 1536 * 4));
  char*  zblk   = (char*)(ws + alloc(4096));       // cnt(4) | bmask(4) | maskg(3072)
  int*      cnt   = (int*)zblk;
  unsigned* bmask = (unsigned*)(zblk + 4);
  unsigned* maskg = (unsigned*)(zblk + 8);
  int*   wl     = (int*)(ws + alloc(24576 * 4));
  float* tsum   = (float*)(ws + alloc(24576 * 4));
  float* tsq    = (float*)(ws + alloc(24576 * 4));
  u16*   xbf    = (u16*)(ws + alloc((size_t)MTOT * DIMC * 2));
  u16*   n2bf   = (u16*)(ws + alloc((size_t)MTOT * DIMC * 2));
  float* vxt    = (float*)(ws + alloc((size_t)MTOT * DIMC * 4));
  float* newm   = (float*)(ws + alloc((size_t)MTOT * DIMC * 4));
  float* new2   = (float*)(ws + alloc((size_t)MTOT * DIMC * 4));
  u16*   hbf    = (u16*)vxt;   // overlay: h (38.5 MB) over vxt+newm (both dead by fc1)
  if (ws_size < o) return;

  hipMemsetAsync(zblk, 0, 4096, stream);

  // prep: DFT frag matrices + v_w/fc2w cvt + x cvt
  prep_k<<<7962, 256, 0, stream>>>(v_w, fc2w, x, vwbf, fc2bf, xbf, Ffb, Gfb);
  // vx = x @ v_w^T, transpose-written as (b, g, n)
  gemm_k<0><<<336, 256, 0, stream>>>(xbf, vwbf, nullptr, nullptr, vxt, DIMC, DIMC, DIMC, 6);
  // MFMA screen -> worklist
  checkmfma_k<<<1536, 64, 0, stream>>>(vxt, kern, Ffb, Gfb, cnt, wl);
  // exact ISTA for flagged tiles + per-tile BN1 sums + masks
  slow_k<<<1024, 64, 0, stream>>>(vxt, kern, kern2, Lb, cnt, wl, newm,
                                  tsum, tsq, maskg, bmask);
  // BN1 finalize + c0 = projW @ sh1 + proj_b
  stats1c0_k<<<3, 256, 0, stream>>>(tsum, tsq, maskg, n1g, n1b, proj_w, proj_b, sc1, c0);
  // new2 = x + c0 + sparse corr; f32 + bf16; BN2 partial sums
  bnb_k<<<dim3(28, 32), 256, 0, stream>>>(x, c0, sc1, maskg, bmask, newm, proj_w,
                                          new2, n2bf, part);
  // BN2 finalize
  stats2fin_k<<<3, 256, 0, stream>>>(part, n2g, n2b, sc2, sh2);
  // fold BN2 into fc1 (d0 + scaled weights)
  foldfc1_k<<<2316, 256, 0, stream>>>(fc1w, fc1b, sc2, sh2, fc1s, d0);
  // h = gelu(new2 @ fc1s^T + d0)
  gemm_k<2><<<1344, 256, 0, stream>>>(n2bf, fc1s, d0, nullptr, hbf, HIDC, DIMC, DIMC, 24);
  // out = new2 + h @ fc2^T + fc2_b
  gemm_k<1><<<336, 256, 0, stream>>>(hbf, fc2bf, fc2b, new2, out, DIMC, HIDC, HIDC, 6);
}

// Round 11
// 305.837 us; speedup vs baseline: 1.1658x; 1.1658x over previous
//
#include <hip/hip_runtime.h>
#include <cmath>

typedef unsigned short u16;
typedef __bf16 bf16x8 __attribute__((ext_vector_type(8)));
typedef float f32x4 __attribute__((ext_vector_type(4)));
typedef float float4v __attribute__((ext_vector_type(4)));
typedef u16 ushort4v __attribute__((ext_vector_type(4)));
typedef u16 ushort8v __attribute__((ext_vector_type(8)));

#define DIMC 768
#define NP 196
#define MTOT 6272         // 32*196
#define HIDC 3072
#define LAMC 3.5f

__device__ const float C14d[14] = {
  1.0f, 0.9009688679024191f, 0.6234898018587336f, 0.22252093395631445f,
  -0.22252093395631445f, -0.6234898018587336f, -0.9009688679024191f, -1.0f,
  -0.9009688679024191f, -0.6234898018587336f, -0.22252093395631445f,
  0.22252093395631445f, 0.6234898018587336f, 0.9009688679024191f
};
__device__ const float S14d[14] = {
  0.0f, 0.43388373911755823f, 0.7818314824680298f, 0.9749279121818236f,
  0.9749279121818236f, 0.7818314824680298f, 0.43388373911755823f, 0.0f,
  -0.43388373911755823f, -0.7818314824680298f, -0.9749279121818236f,
  -0.9749279121818236f, -0.7818314824680298f, -0.43388373911755823f
};

__device__ __forceinline__ u16 f2bf(float f) {
  unsigned u = __builtin_bit_cast(unsigned, f);
  unsigned r = u + 0x7FFFu + ((u >> 16) & 1u);
  return (u16)(r >> 16);
}

typedef const __attribute__((address_space(1))) u16* gas_p;
typedef __attribute__((address_space(3))) u16* las_p;
__device__ __forceinline__ void gl16(const u16* g, u16* l) {
  __builtin_amdgcn_global_load_lds((gas_p)g, (las_p)l, 16, 0, 0);
}

// ---------------- fused prep: initfg + weight cvt + x cvt (1 dispatch) ------
__global__ __launch_bounds__(256) void prep_k(
    const float* __restrict__ v_w, const float* __restrict__ fc2w,
    const float* __restrict__ x,
    u16* __restrict__ vwbf, u16* __restrict__ fc2bf, u16* __restrict__ xbf,
    u16* __restrict__ Ff, u16* __restrict__ Gf) {
  const int bid = blockIdx.x, t = threadIdx.x;
  if (bid < 378) {                           // initfg
    int idx = bid * 256 + t;
    if (idx < 50176) {                       // Ff: 14*7*64*8
      int j = idx & 7, lane = (idx >> 3) & 63;
      int mk = idx >> 9, k0 = mk % 7, m0 = mk / 7;
      int s = m0 * 16 + (lane & 15);
      int q = k0 * 32 + (lane >> 4) * 8 + j;
      float v = 0.f;
      if (q < 196) {
        int kr = s >> 4, f = (s >> 1) & 7, r = q / 14, c = q % 14;
        int th = (kr * r + f * c) % 14;
        v = (s & 1) ? -S14d[th] : C14d[th];
      }
      Ff[idx] = f2bf(v);
    } else {                                 // Gf: 13*7*64*8
      int t2 = idx - 50176;
      int j = t2 & 7, lane = (t2 >> 3) & 63;
      int pk = t2 >> 9, k0 = pk % 7, p0 = pk / 7;
      int p = p0 * 16 + (lane & 15);
      int s = k0 * 32 + (lane >> 4) * 8 + j;
      float v = 0.f;
      if (p < 196) {
        int kr = s >> 4, f = (s >> 1) & 7, r = p / 14, c = p % 14;
        int th = (kr * r + f * c) % 14;
        float w = (f == 0 || f == 7) ? 1.f : 2.f;
        v = (w * (1.f / 196.f)) * ((s & 1) ? -S14d[th] : C14d[th]);
      }
      Gf[t2] = f2bf(v);
    }
  } else if (bid < 3258) {                   // v_w + fc2w -> bf16
    int idx = (bid - 378) * 256 + t;
    const float* s; u16* d; int base;
    if (idx < 147456) { s = v_w; d = vwbf; base = 0; }
    else              { s = fc2w; d = fc2bf; base = 147456; }
    int i4 = (idx - base) * 4;
    float4v v = *(const float4v*)(s + i4);
    ushort4v o;
#pragma unroll
    for (int j = 0; j < 4; ++j) o[j] = f2bf(v[j]);
    *(ushort4v*)(d + i4) = o;
  } else {                                   // x -> bf16
    int idx = (bid - 3258) * 256 + t;
    int i4 = idx * 4;
    float4v v = *(const float4v*)(x + i4);
    ushort4v o;
#pragma unroll
    for (int j = 0; j < 4; ++j) o[j] = f2bf(v[j]);
    *(ushort4v*)(xbf + i4) = o;
  }
}

// ---------------- 128x128 bf16 MFMA GEMM (R3 body + XCD decode + LDS swizzle)
// Swizzle (rule #21): linear gl16 dest + inverse-permuted SOURCE + permuted
// read. swz(r) = (r^(r>>2))&3. Lane stages global (row=lane>>2,
// kslot=(lane&3)^swz(lane>>2)); read col = l4^swz(l15). Banks -> 2-way (free).
// EPI 0: f32x4 transpose-write vxt[(b*768+n)*196+np]; EPI 1: +bias+res f32;
// EPI 2: bf16 gelu(acc+bias)
template<int EPI>
__global__ __launch_bounds__(256) void gemm_k(
    const u16* __restrict__ A, const u16* __restrict__ Bw,
    const float* __restrict__ bias, const float* __restrict__ res,
    void* __restrict__ Cp, int Nr, int Kr, int ld, int NB) {
  __shared__ __attribute__((aligned(16))) u16 As[128 * 32];
  __shared__ __attribute__((aligned(16))) u16 Bs[128 * 32];
  const int t = threadIdx.x;
  const int wid = t >> 6, lane = t & 63;

  const int bid = blockIdx.x;
  const int xcd = bid & 7, j = bid >> 3;
  const int bmi = xcd + 8 * (j / NB);
  if (bmi >= 49) return;
  const int bn = (j % NB) * 128, bm = bmi * 128;

  const int wm = (wid >> 1) * 64, wn = (wid & 1) * 64;
  const int l15 = lane & 15, l4 = lane >> 4;
  const int srow = lane >> 2;
  const int sw_s = ((lane >> 2) ^ (lane >> 4)) & 3;          // swz(lane>>2)
  const int scol = ((lane & 3) ^ sw_s) * 8;
  const int sw_r = (l15 ^ (l15 >> 2)) & 3;                   // swz(l15)
  const int rcol = (l4 ^ sw_r) * 8;

  f32x4 acc[4][4];
#pragma unroll
  for (int a = 0; a < 4; ++a)
#pragma unroll
    for (int b2 = 0; b2 < 4; ++b2) acc[a][b2] = (f32x4){0.f, 0.f, 0.f, 0.f};

  const u16* gA0 = A + (size_t)(bm + wid * 16 + srow) * ld + scol;
  const u16* gB0 = Bw + (size_t)(bn + wid * 16 + srow) * ld + scol;
  u16* lA = As + wid * 512;
  u16* lB = Bs + wid * 512;

  for (int k0 = 0; k0 < Kr; k0 += 32) {
    gl16(gA0 + k0, lA);
    gl16(gA0 + (size_t)64 * ld + k0, lA + 2048);
    gl16(gB0 + k0, lB);
    gl16(gB0 + (size_t)64 * ld + k0, lB + 2048);
    __syncthreads();

    bf16x8 af[4], bfv[4];
#pragma unroll
    for (int mb = 0; mb < 4; ++mb)
      af[mb] = *(const bf16x8*)&As[(wm + mb * 16 + l15) * 32 + rcol];
#pragma unroll
    for (int nb = 0; nb < 4; ++nb)
      bfv[nb] = *(const bf16x8*)&Bs[(wn + nb * 16 + l15) * 32 + rcol];
#pragma unroll
    for (int mb = 0; mb < 4; ++mb)
#pragma unroll
      for (int nb = 0; nb < 4; ++nb)
        acc[mb][nb] = __builtin_amdgcn_mfma_f32_16x16x32_bf16(af[mb], bfv[nb], acc[mb][nb], 0, 0, 0);
    __syncthreads();
  }

#pragma unroll
  for (int mb = 0; mb < 4; ++mb) {
#pragma unroll
    for (int nb = 0; nb < 4; ++nb) {
      int n = bn + wn + nb * 16 + l15;
      if (EPI == 0) {
        int m0 = bm + wm + mb * 16 + l4 * 4;
        int bb = m0 / 196, np0 = m0 - bb * 196;
        *(float4v*)&((float*)Cp)[((size_t)bb * DIMC + n) * 196 + np0] =
            (float4v){acc[mb][nb][0], acc[mb][nb][1], acc[mb][nb][2], acc[mb][nb][3]};
      } else {
#pragma unroll
        for (int r = 0; r < 4; ++r) {
          int m = bm + wm + mb * 16 + l4 * 4 + r;
          float v = acc[mb][nb][r];
          if (EPI == 1) {
            ((float*)Cp)[(size_t)m * Nr + n] = v + bias[n] + res[(size_t)m * Nr + n];
          } else {
            float vb = v + bias[n];
            float ge = 0.5f * vb * (1.f + erff(vb * 0.70710678118654752f));
            ((u16*)Cp)[(size_t)m * Nr + n] = f2bf(ge);
          }
        }
      }
    }
  }
}

// ---------------- MFMA screen: max_i max_p |u_i| per tile, flag > 3.4 ----------
__global__ __launch_bounds__(64) void checkmfma_k(
    const float* __restrict__ vxt, const float* __restrict__ kern,
    const u16* __restrict__ Ff, const u16* __restrict__ Gf,
    int* __restrict__ cnt, int* __restrict__ wl) {
  __shared__ float xf[16 * 228];
  const int lane = threadIdx.x;
  const int wgb = blockIdx.x;
  const int g = wgb >> 1, bhalf = wgb & 1;
  const int tl = lane & 15, h = lane >> 4;
  const float* xbase = vxt + ((size_t)(bhalf * 16 + tl) * DIMC + g) * 196;

  bf16x8 Bx[7];
#pragma unroll
  for (int k0 = 0; k0 < 7; ++k0) {
    int q0 = k0 * 32 + h * 8;
    ushort8v tv;
    if (k0 < 6) {
      float4v f0 = *(const float4v*)(xbase + q0);
      float4v f1 = *(const float4v*)(xbase + q0 + 4);
#pragma unroll
      for (int j = 0; j < 4; ++j) { tv[j] = f2bf(f0[j]); tv[j + 4] = f2bf(f1[j]); }
    } else {
#pragma unroll
      for (int j = 0; j < 8; ++j) {
        int q = q0 + j;
        tv[j] = (q < 196) ? f2bf(xbase[q]) : (u16)0;
      }
    }
    Bx[k0] = __builtin_bit_cast(bf16x8, tv);
  }

  for (int m0 = 0; m0 < 14; ++m0) {
    f32x4 acc = (f32x4){0.f, 0.f, 0.f, 0.f};
#pragma unroll
    for (int k0 = 0; k0 < 7; ++k0) {
      bf16x8 Af = __builtin_bit_cast(bf16x8,
          *(const ushort8v*)(Ff + ((size_t)(m0 * 7 + k0) * 64 + lane) * 8));
      acc = __builtin_amdgcn_mfma_f32_16x16x32_bf16(Af, Bx[k0], acc, 0, 0, 0);
    }
    *(f32x4*)&xf[tl * 228 + m0 * 16 + h * 4] = acc;
  }

  bf16x8 By[5][7];
#pragma unroll
  for (int i = 0; i < 5; ++i) {
    const float* kb = kern + ((size_t)g * 5 + i) * 224;
#pragma unroll
    for (int k0 = 0; k0 < 7; ++k0) {
      f32x4 x0 = *(const f32x4*)&xf[tl * 228 + k0 * 32 + h * 8];
      f32x4 x1 = *(const f32x4*)&xf[tl * 228 + k0 * 32 + h * 8 + 4];
      int mb = k0 * 16 + h * 4;
      float2 ka = *(const float2*)(kb + (mb + 0) * 2);
      float2 kc = *(const float2*)(kb + (mb + 1) * 2);
      float2 ke = *(const float2*)(kb + (mb + 2) * 2);
      float2 kg = *(const float2*)(kb + (mb + 3) * 2);
      ushort8v tv;
      tv[0] = f2bf(ka.x * x0[0] - ka.y * x0[1]);
      tv[1] = f2bf(ka.x * x0[1] + ka.y * x0[0]);
      tv[2] = f2bf(kc.x * x0[2] - kc.y * x0[3]);
      tv[3] = f2bf(kc.x * x0[3] + kc.y * x0[2]);
      tv[4] = f2bf(ke.x * x1[0] - ke.y * x1[1]);
      tv[5] = f2bf(ke.x * x1[1] + ke.y * x1[0]);
      tv[6] = f2bf(kg.x * x1[2] - kg.y * x1[3]);
      tv[7] = f2bf(kg.x * x1[3] + kg.y * x1[2]);
      By[i][k0] = __builtin_bit_cast(bf16x8, tv);
    }
  }

  float vmax = 0.f;
  for (int p0 = 0; p0 < 13; ++p0) {
    f32x4 a0 = (f32x4){0.f, 0.f, 0.f, 0.f};
    f32x4 a1 = a0, a2 = a0, a3 = a0, a4 = a0;
#pragma unroll
    for (int k0 = 0; k0 < 7; ++k0) {
      bf16x8 Ag = __builtin_bit_cast(bf16x8,
          *(const ushort8v*)(Gf + ((size_t)(p0 * 7 + k0) * 64 + lane) * 8));
      a0 = __builtin_amdgcn_mfma_f32_16x16x32_bf16(Ag, By[0][k0], a0, 0, 0, 0);
      a1 = __builtin_amdgcn_mfma_f32_16x16x32_bf16(Ag, By[1][k0], a1, 0, 0, 0);
      a2 = __builtin_amdgcn_mfma_f32_16x16x32_bf16(Ag, By[2][k0], a2, 0, 0, 0);
      a3 = __builtin_amdgcn_mfma_f32_16x16x32_bf16(Ag, By[3][k0], a3, 0, 0, 0);
      a4 = __builtin_amdgcn_mfma_f32_16x16x32_bf16(Ag, By[4][k0], a4, 0, 0, 0);
    }
#pragma unroll
    for (int r = 0; r < 4; ++r) {
      vmax = fmaxf(vmax, fabsf(a0[r]));
      vmax = fmaxf(vmax, fabsf(a1[r]));
      vmax = fmaxf(vmax, fabsf(a2[r]));
      vmax = fmaxf(vmax, fabsf(a3[r]));
      vmax = fmaxf(vmax, fabsf(a4[r]));
    }
  }
  vmax = fmaxf(vmax, __shfl_xor(vmax, 16));
  vmax = fmaxf(vmax, __shfl_xor(vmax, 32));
  if (lane < 16 && vmax > (LAMC - 0.1f)) {
    int idx = atomicAdd(cnt, 1);
    wl[idx] = g * 32 + bhalf * 16 + lane;
  }
}

// ---------------- full ISTA for flagged tiles + fused tile sums -------------
__global__ __launch_bounds__(64) void slow_k(
    const float* __restrict__ vxt, const float* __restrict__ kern,
    const float* __restrict__ kern2, const float* __restrict__ Lbuf,
    const int* __restrict__ cnt, const int* __restrict__ wl,
    float* __restrict__ outp,
    float* __restrict__ tsum, float* __restrict__ tsq,
    unsigned* __restrict__ maskg, unsigned* __restrict__ bmask) {
  const int ntile = *cnt;
  if ((int)blockIdx.x >= ntile) return;
  const int t = threadIdx.x;
  __shared__ float TC[196], TSn[196];
  __shared__ float xs[196];
  __shared__ float t1R[112], t1I[112];
  __shared__ float t2R[112], t2I[112];
  __shared__ float zr[112], zi[112];
  __shared__ float kR[5][112], kI[5][112];
  __shared__ float uu[5][196];
  __shared__ float ss[5][196];
  __shared__ float k2R[112], k2I[112];

  for (int i = t; i < 196; i += 64) {
    int a = i / 14, c = i - (i / 14) * 14;
    int m = (a * c) % 14;
    TC[i] = C14d[m]; TSn[i] = S14d[m];
  }

  auto rowsFwd = [&](const float* xsrc) {
    for (int i = t; i < 112; i += 64) {
      int r = i >> 3, f = i & 7;
      const float* xp = xsrc + r * 14;
      const float* tc = &TC[f * 14]; const float* tsn = &TSn[f * 14];
      float ar = 0.f, ai = 0.f;
#pragma unroll
      for (int c = 0; c < 14; ++c) { float xv = xp[c]; ar += xv * tc[c]; ai -= xv * tsn[c]; }
      t1R[i] = ar; t1I[i] = ai;
    }
    __syncthreads();
  };
  auto colsFwd = [&](float* oR, float* oI) {
    for (int i = t; i < 112; i += 64) {
      int kr = i >> 3, f = i & 7;
      const float* tc = &TC[kr * 14]; const float* tsn = &TSn[kr * 14];
      float br = 0.f, bi = 0.f;
#pragma unroll
      for (int r = 0; r < 14; ++r) {
        float xr = t1R[r * 8 + f], xi = t1I[r * 8 + f];
        br += tc[r] * xr + tsn[r] * xi;
        bi += tc[r] * xi - tsn[r] * xr;
      }
      oR[i] = br; oI[i] = bi;
    }
    __syncthreads();
  };
  auto colsInv = [&]() {
    for (int i = t; i < 112; i += 64) {
      int r = i >> 3, f = i & 7;
      const float* tc = &TC[r * 14]; const float* tsn = &TSn[r * 14];
      float br = 0.f, bi = 0.f;
#pragma unroll
      for (int kr = 0; kr < 14; ++kr) {
        float xr = t1R[kr * 8 + f], xi = t1I[kr * 8 + f];
        br += tc[kr] * xr - tsn[kr] * xi;
        bi += tc[kr] * xi + tsn[kr] * xr;
      }
      t2R[i] = br; t2I[i] = bi;
    }
    __syncthreads();
  };
  auto rowVal = [&](int r, int c) -> float {
    const float* pR = &t2R[r * 8]; const float* pI = &t2I[r * 8];
    float v = pR[0] + ((c & 1) ? -pR[7] : pR[7]);
    float s2 = 0.f;
#pragma unroll
    for (int f = 1; f < 7; ++f) s2 += pR[f] * TC[f * 14 + c] - pI[f] * TSn[f * 14 + c];
    return (v + 2.f * s2) * (1.0f / 196.0f);
  };

  for (int widx = blockIdx.x; widx < ntile; widx += gridDim.x) {
    const int tile = wl[widx];
    const int g = tile >> 5, b = tile & 31;
    __syncthreads();
    for (int i = t; i < 560; i += 64) {
      int ii = i / 112, p = i - ii * 112;
      const float* kp = kern + ((size_t)g * 5 + ii) * 224 + p * 2;
      kR[ii][p] = kp[0]; kI[ii][p] = kp[1];
    }
    for (int i = t; i < 196; i += 64) xs[i] = vxt[((size_t)b * DIMC + g) * 196 + i];
    for (int i = t; i < 112; i += 64) {
      k2R[i] = kern2[(size_t)g * 224 + i * 2];
      k2I[i] = kern2[(size_t)g * 224 + i * 2 + 1];
    }
    __syncthreads();

    rowsFwd(xs);
    colsFwd(zr, zi);
    for (int ii = 0; ii < 5; ++ii) {
      for (int i = t; i < 112; i += 64) {
        float a = kR[ii][i], b2 = kI[ii][i];
        t1R[i] = a * zr[i] - b2 * zi[i];
        t1I[i] = a * zi[i] + b2 * zr[i];
      }
      __syncthreads();
      colsInv();
      for (int i = t; i < 196; i += 64) uu[ii][i] = rowVal(i / 14, i - (i / 14) * 14);
      __syncthreads();
    }

    const float invL = 1.0f / Lbuf[g];
    const float thr = LAMC * invL;
    {
      float* up = &uu[0][0];
      float* sp = &ss[0][0];
      for (int i = t; i < 980; i += 64) {
        float v = up[i];
        float a = fabsf(v) - LAMC;
        sp[i] = a > 0.f ? copysignf(a, v) : 0.f;
      }
    }
    __syncthreads();

    for (int iter = 0; iter < 4; ++iter) {
      for (int i = t; i < 112; i += 64) { zr[i] = 0.f; zi[i] = 0.f; }
      __syncthreads();
      for (int ii = 0; ii < 5; ++ii) {
        rowsFwd(&ss[ii][0]);
        colsFwd(t2R, t2I);
        for (int i = t; i < 112; i += 64) {
          float a = kR[ii][i], b2 = kI[ii][i];
          zr[i] += a * t2R[i] + b2 * t2I[i];
          zi[i] += a * t2I[i] - b2 * t2R[i];
        }
        __syncthreads();
      }
      if (iter == 3) break;
      for (int ii = 0; ii < 5; ++ii) {
        for (int i = t; i < 112; i += 64) {
          float a = kR[ii][i], b2 = kI[ii][i];
          t1R[i] = a * zr[i] - b2 * zi[i];
          t1I[i] = a * zi[i] + b2 * zr[i];
        }
        __syncthreads();
        colsInv();
        for (int i = t; i < 196; i += 64) {
          float v = rowVal(i / 14, i - (i / 14) * 14);
          float sv = ss[ii][i] - (v - uu[ii][i]) * invL;
          float aa = fabsf(sv) - thr;
          ss[ii][i] = aa > 0.f ? copysignf(aa, sv) : 0.f;
        }
        __syncthreads();
      }
    }

    if (t < 28) {
      int kr = t >> 1, f = (t & 1) * 7;
      int d = kr * 8 + f;
      int srci = ((14 - kr) % 14) * 8 + f;
      float pr = 0.5f * (zr[d] + zr[srci]);
      float pi = 0.5f * (zi[d] - zi[srci]);
      zr[d] = pr; zi[d] = pi;
    }
    __syncthreads();
    for (int i = t; i < 112; i += 64) {
      float a = k2R[i], b2 = k2I[i];
      t1R[i] = a * zr[i] - b2 * zi[i];
      t1I[i] = a * zi[i] + b2 * zr[i];
    }
    __syncthreads();
    colsInv();
    float sacc = 0.f, qacc = 0.f;
    for (int i = t; i < 196; i += 64) {
      float v = rowVal(i / 14, i - (i / 14) * 14);
      outp[((size_t)(b * 196 + i)) * DIMC + g] = v;
      sacc += v; qacc += v * v;
    }
#pragma unroll
    for (int off = 32; off; off >>= 1) {
      sacc += __shfl_xor(sacc, off);
      qacc += __shfl_xor(qacc, off);
    }
    if (t == 0) {
      tsum[tile] = sacc; tsq[tile] = qacc;
      atomicOr(&maskg[g], 1u << b);
      atomicOr(bmask, 1u << b);
    }
  }
}

// ---------------- BN1 finalize + c0 in one dispatch (3 blocks) --------------
__global__ __launch_bounds__(256) void stats1c0_k(
    const float* __restrict__ tsum, const float* __restrict__ tsq,
    const unsigned* __restrict__ maskg,
    const float* __restrict__ gam, const float* __restrict__ bet,
    const float* __restrict__ projw, const float* __restrict__ pb,
    float* __restrict__ sc1, float* __restrict__ c0) {
  __shared__ float sh1s[768];
  const int t = threadIdx.x;
  for (int c = t; c < DIMC; c += 256) {
    unsigned mask = maskg[c];
    float S = 0.f, Q = 0.f;
    if (mask) {
      for (int b = 0; b < 32; ++b)
        if ((mask >> b) & 1) { S += tsum[c * 32 + b]; Q += tsq[c * 32 + b]; }
    }
    float m = S * (1.0f / 6272.0f);
    float v = fmaxf(Q * (1.0f / 6272.0f) - m * m, 0.f);
    float rs = rsqrtf(v + 1e-5f);
    float sc = gam[c] * rs;
    sh1s[c] = bet[c] - m * sc;
    if (blockIdx.x == 0) sc1[c] = sc;
  }
  __syncthreads();
  int n = blockIdx.x * 256 + t;
  const float* row = projw + (size_t)n * DIMC;
  float s = 0.f;
  for (int g = 0; g < DIMC; g += 4) {
    float4v r = *(const float4v*)(row + g);
    s += r[0] * sh1s[g] + r[1] * sh1s[g + 1] + r[2] * sh1s[g + 2] + r[3] * sh1s[g + 3];
  }
  c0[n] = s + pb[n];
}

// ---------------- fused: new2 = x + c0 + sparse-corr; f32+bf16; BN2 partials
__global__ __launch_bounds__(256) void bnb_k(
    const float* __restrict__ x, const float* __restrict__ c0,
    const float* __restrict__ sc1, const unsigned* __restrict__ maskg,
    const unsigned* __restrict__ bmask, const float* __restrict__ newm,
    const float* __restrict__ projw,
    float* __restrict__ new2, u16* __restrict__ n2bf,
    float* __restrict__ part) {
  const int jb = blockIdx.x, b = blockIdx.y, t = threadIdx.x;
  __shared__ unsigned gm[24];
  __shared__ float c0s[768];
  const bool hasb = ((*bmask >> b) & 1u) != 0u;
  if (t < 24) {
    unsigned w = 0;
    if (hasb)
      for (int j2 = 0; j2 < 32; ++j2) w |= ((maskg[t * 32 + j2] >> b) & 1u) << j2;
    gm[t] = w;
  }
  for (int c = t; c < 768; c += 256) c0s[c] = c0[c];
  __syncthreads();

  float S0 = 0, S1 = 0, S2 = 0, Q0 = 0, Q1 = 0, Q2 = 0;
  for (int mr = 0; mr < 7; ++mr) {
    size_t row = ((size_t)b * 196 + jb * 7 + mr) * DIMC;
#pragma unroll
    for (int j2 = 0; j2 < 3; ++j2) {
      int n = t + j2 * 256;
      float v = x[row + n] + c0s[n];
      if (hasb) {
        for (int w = 0; w < 24; ++w) {
          unsigned bits = gm[w];
          while (bits) {
            int g = w * 32 + __builtin_ctz(bits);
            bits &= bits - 1;
            v += sc1[g] * newm[row + g] * projw[(size_t)n * DIMC + g];
          }
        }
      }
      new2[row + n] = v;
      n2bf[row + n] = f2bf(v);
      if (j2 == 0) { S0 += v; Q0 += v * v; }
      else if (j2 == 1) { S1 += v; Q1 += v * v; }
      else { S2 += v; Q2 += v * v; }
    }
  }
  float* p = part + (size_t)(b * 28 + jb) * 1536;
  p[t] = S0; p[t + 256] = S1; p[t + 512] = S2;
  p[768 + t] = Q0; p[768 + 256 + t] = Q1; p[768 + 512 + t] = Q2;
}

// ---------------- BN2 reduce stage A: collapse jb (28 iters, 192 blocks) ----
__global__ __launch_bounds__(256) void red2_k(const float* __restrict__ part,
                                              float* __restrict__ part2) {
  int slot = blockIdx.x * 256 + threadIdx.x;   // 0..1535
  int b = blockIdx.y;
  float s = 0.f;
  const float* p = part + (size_t)(b * 28) * 1536 + slot;
  for (int jb = 0; jb < 28; ++jb) s += p[(size_t)jb * 1536];
  part2[(size_t)b * 1536 + slot] = s;
}

// ---------------- BN2 finalize (3 blocks, 32 iters) -------------------------
__global__ __launch_bounds__(256) void stats2fin_k(const float* __restrict__ part2,
    const float* __restrict__ gam, const float* __restrict__ bet,
    float* __restrict__ scale, float* __restrict__ shift) {
  int c = blockIdx.x * 256 + threadIdx.x;
  float S = 0.f, Q = 0.f;
  for (int b = 0; b < 32; ++b) {
    S += part2[(size_t)b * 1536 + c];
    Q += part2[(size_t)b * 1536 + 768 + c];
  }
  float m = S * (1.0f / 6272.0f);
  float v = fmaxf(Q * (1.0f / 6272.0f) - m * m, 0.f);
  float rs = rsqrtf(v + 1e-5f);
  float sc = gam[c] * rs;
  scale[c] = sc;
  shift[c] = bet[c] - m * sc;
}

// ---------------- fold BN2 into fc1: d0 + fc1s (one dispatch) ---------------
__global__ __launch_bounds__(256) void foldfc1_k(const float* __restrict__ fc1w,
    const float* __restrict__ fc1b, const float* __restrict__ sc2,
    const float* __restrict__ sh2, u16* __restrict__ fc1s,
    float* __restrict__ d0) {
  const int bid = blockIdx.x, t = threadIdx.x;
  if (bid < 12) {
    int n = bid * 256 + t;
    const float* row = fc1w + (size_t)n * DIMC;
    float s = 0.f;
    for (int k = 0; k < DIMC; k += 4) {
      float4v r = *(const float4v*)(row + k);
      float4v h = *(const float4v*)(sh2 + k);
      s += r[0] * h[0] + r[1] * h[1] + r[2] * h[2] + r[3] * h[3];
    }
    d0[n] = s + fc1b[n];
  } else {
    int idx = (bid - 12) * 256 + t;
    int i4 = idx * 4;
    int k = i4 % DIMC;
    float4v v = *(const float4v*)(fc1w + i4);
    float4v s = *(const float4v*)(sc2 + k);
    v = v * s;
    ushort4v o;
#pragma unroll
    for (int j = 0; j < 4; ++j) o[j] = f2bf(v[j]);
    *(ushort4v*)(fc1s + i4) = o;
  }
}

// ---------------- launch ----------------
extern "C" void kernel_launch(void* const* d_in, const int* in_sizes, int n_in,
                              void* d_out, int out_size, void* d_ws, size_t ws_size,
                              hipStream_t stream) {
  (void)in_sizes; (void)n_in; (void)out_size;
  const float* x      = (const float*)d_in[0];
  const float* v_w    = (const float*)d_in[1];
  const float* proj_w = (const float*)d_in[2];
  const float* proj_b = (const float*)d_in[3];
  const float* kern   = (const float*)d_in[4];
  const float* kern2  = (const float*)d_in[5];
  const float* n1g    = (const float*)d_in[6];
  const float* n1b    = (const float*)d_in[7];
  const float* n2g    = (const float*)d_in[8];
  const float* n2b    = (const float*)d_in[9];
  const float* fc1w   = (const float*)d_in[10];
  const float* fc1b   = (const float*)d_in[11];
  const float* fc2w   = (const float*)d_in[12];
  const float* fc2b   = (const float*)d_in[13];
  const float* Lb     = (const float*)d_in[14];
  float* out = (float*)d_out;

  char* ws = (char*)d_ws;
  size_t o = 0;
  auto alloc = [&](size_t bytes) { size_t r = o; o += (bytes + 255) & ~(size_t)255; return r; };
  u16*   vwbf   = (u16*)(ws + alloc(589824 * 2));
  u16*   fc2bf  = (u16*)(ws + alloc(2359296 * 2));
  u16*   fc1s   = (u16*)(ws + alloc(2359296 * 2));
  u16*   Ffb    = (u16*)(ws + alloc(50176 * 2));
  u16*   Gfb    = (u16*)(ws + alloc(46592 * 2));
  float* sc1    = (float*)(ws + alloc(768 * 4));
  float* sc2    = (float*)(ws + alloc(768 * 4));
  float* sh2    = (float*)(ws + alloc(768 * 4));
  float* c0     = (float*)(ws + alloc(768 * 4));
  float* d0     = (float*)(ws + alloc(3072 * 4));
  float* part   = (float*)(ws + alloc((size_t)896 * 1536 * 4));
  float* part2  = (float*)(ws + alloc((size_t)32 * 1536 * 4));
  char*  zblk   = (char*)(ws + alloc(4096));       // cnt(4) | bmask(4) | maskg(3072)
  int*      cnt   = (int*)zblk;
  unsigned* bmask = (unsigned*)(zblk + 4);
  unsigned* maskg = (unsigned*)(zblk + 8);
  int*   wl     = (int*)(ws + alloc(24576 * 4));
  float* tsum   = (float*)(ws + alloc(24576 * 4));
  float* tsq    = (float*)(ws + alloc(24576 * 4));
  u16*   xbf    = (u16*)(ws + alloc((size_t)MTOT * DIMC * 2));
  u16*   n2bf   = (u16*)(ws + alloc((size_t)MTOT * DIMC * 2));
  float* vxt    = (float*)(ws + alloc((size_t)MTOT * DIMC * 4));
  float* newm   = (float*)(ws + alloc((size_t)MTOT * DIMC * 4));
  float* new2   = (float*)(ws + alloc((size_t)MTOT * DIMC * 4));
  u16*   hbf    = (u16*)vxt;   // overlay: h (38.5 MB) over vxt+newm (both dead by fc1)
  if (ws_size < o) return;

  hipMemsetAsync(zblk, 0, 4096, stream);

  // prep: DFT frag matrices + v_w/fc2w cvt + x cvt
  prep_k<<<7962, 256, 0, stream>>>(v_w, fc2w, x, vwbf, fc2bf, xbf, Ffb, Gfb);
  // vx = x @ v_w^T, transpose-written as (b, g, n)
  gemm_k<0><<<336, 256, 0, stream>>>(xbf, vwbf, nullptr, nullptr, vxt, DIMC, DIMC, DIMC, 6);
  // MFMA screen -> worklist
  checkmfma_k<<<1536, 64, 0, stream>>>(vxt, kern, Ffb, Gfb, cnt, wl);
  // exact ISTA for flagged tiles + per-tile BN1 sums + masks
  slow_k<<<1024, 64, 0, stream>>>(vxt, kern, kern2, Lb, cnt, wl, newm,
                                  tsum, tsq, maskg, bmask);
  // BN1 finalize + c0 = projW @ sh1 + proj_b
  stats1c0_k<<<3, 256, 0, stream>>>(tsum, tsq, maskg, n1g, n1b, proj_w, proj_b, sc1, c0);
  // new2 = x + c0 + sparse corr; f32 + bf16; BN2 partial sums
  bnb_k<<<dim3(28, 32), 256, 0, stream>>>(x, c0, sc1, maskg, bmask, newm, proj_w,
                                          new2, n2bf, part);
  // BN2 reduce (two-stage, parallel)
  red2_k<<<dim3(6, 32), 256, 0, stream>>>(part, part2);
  stats2fin_k<<<3, 256, 0, stream>>>(part2, n2g, n2b, sc2, sh2);
  // fold BN2 into fc1 (d0 + scaled weights)
  foldfc1_k<<<2316, 256, 0, stream>>>(fc1w, fc1b, sc2, sh2, fc1s, d0);
  // h = gelu(new2 @ fc1s^T + d0)
  gemm_k<2><<<1344, 256, 0, stream>>>(n2bf, fc1s, d0, nullptr, hbf, HIDC, DIMC, DIMC, 24);
  // out = new2 + h @ fc2^T + fc2_b
  gemm_k<1><<<336, 256, 0, stream>>>(hbf, fc2bf, fc2b, new2, out, DIMC, HIDC, HIDC, 6);
}

// Round 12
// 273.425 us; speedup vs baseline: 1.3040x; 1.1185x over previous
//
#include <hip/hip_runtime.h>
#include <cmath>

typedef unsigned short u16;
typedef __bf16 bf16x8 __attribute__((ext_vector_type(8)));
typedef float f32x4 __attribute__((ext_vector_type(4)));
typedef float float4v __attribute__((ext_vector_type(4)));
typedef u16 ushort4v __attribute__((ext_vector_type(4)));
typedef u16 ushort8v __attribute__((ext_vector_type(8)));

#define DIMC 768
#define NP 196
#define MTOT 6272         // 32*196 = 98*64
#define HIDC 3072
#define LAMC 3.5f

__device__ const float C14d[14] = {
  1.0f, 0.9009688679024191f, 0.6234898018587336f, 0.22252093395631445f,
  -0.22252093395631445f, -0.6234898018587336f, -0.9009688679024191f, -1.0f,
  -0.9009688679024191f, -0.6234898018587336f, -0.22252093395631445f,
  0.22252093395631445f, 0.6234898018587336f, 0.9009688679024191f
};
__device__ const float S14d[14] = {
  0.0f, 0.43388373911755823f, 0.7818314824680298f, 0.9749279121818236f,
  0.9749279121818236f, 0.7818314824680298f, 0.43388373911755823f, 0.0f,
  -0.43388373911755823f, -0.7818314824680298f, -0.9749279121818236f,
  -0.9749279121818236f, -0.7818314824680298f, -0.43388373911755823f
};

__device__ __forceinline__ u16 f2bf(float f) {
  unsigned u = __builtin_bit_cast(unsigned, f);
  unsigned r = u + 0x7FFFu + ((u >> 16) & 1u);
  return (u16)(r >> 16);
}

// fragment-order index: element (row m, col k) of an (M x K) operand ->
// chunk ((m>>4)*(K>>5) + (k>>5)), lane ((m&15) + ((k>>3)&3)*16), j = k&7
__device__ __forceinline__ size_t fidx(int m, int k, int K) {
  return ((size_t)(m >> 4) * (K >> 5) + (k >> 5)) * 512 +
         (size_t)((((k >> 3) & 3) * 16 + (m & 15)) * 8 + (k & 7));
}

// ---------------- fused prep: initfg + frag-pack x, v_w, fc2w ---------------
__global__ __launch_bounds__(256) void prep_k(
    const float* __restrict__ v_w, const float* __restrict__ fc2w,
    const float* __restrict__ x,
    u16* __restrict__ vwf, u16* __restrict__ fc2f, u16* __restrict__ xf,
    u16* __restrict__ Ff, u16* __restrict__ Gf) {
  const int bid = blockIdx.x, t = threadIdx.x;
  if (bid < 378) {                           // DFT frag matrices
    int idx = bid * 256 + t;
    if (idx < 50176) {
      int j = idx & 7, lane = (idx >> 3) & 63;
      int mk = idx >> 9, k0 = mk % 7, m0 = mk / 7;
      int s = m0 * 16 + (lane & 15);
      int q = k0 * 32 + (lane >> 4) * 8 + j;
      float v = 0.f;
      if (q < 196) {
        int kr = s >> 4, f = (s >> 1) & 7, r = q / 14, c = q % 14;
        int th = (kr * r + f * c) % 14;
        v = (s & 1) ? -S14d[th] : C14d[th];
      }
      Ff[idx] = f2bf(v);
    } else {
      int t2 = idx - 50176;
      int j = t2 & 7, lane = (t2 >> 3) & 63;
      int pk = t2 >> 9, k0 = pk % 7, p0 = pk / 7;
      int p = p0 * 16 + (lane & 15);
      int s = k0 * 32 + (lane >> 4) * 8 + j;
      float v = 0.f;
      if (p < 196) {
        int kr = s >> 4, f = (s >> 1) & 7, r = p / 14, c = p % 14;
        int th = (kr * r + f * c) % 14;
        float w = (f == 0 || f == 7) ? 1.f : 2.f;
        v = (w * (1.f / 196.f)) * ((s & 1) ? -S14d[th] : C14d[th]);
      }
      Gf[t2] = f2bf(v);
    }
    return;
  }
  const float* src; u16* dst; int idx, K;
  if (bid < 666)        { src = v_w;  dst = vwf;  idx = (bid - 378) * 256 + t;  K = DIMC; }
  else if (bid < 1818)  { src = fc2w; dst = fc2f; idx = (bid - 666) * 256 + t;  K = HIDC; }
  else                  { src = x;    dst = xf;   idx = (bid - 1818) * 256 + t; K = DIMC; }
  const int KC = K >> 5;
  int chunk = idx >> 6, l = idx & 63;
  int row = (chunk / KC) * 16 + (l & 15);
  int k0 = (chunk % KC) * 32 + (l >> 4) * 8;
  const float* sp = src + (size_t)row * K + k0;
  float4v f0 = *(const float4v*)sp;
  float4v f1 = *(const float4v*)(sp + 4);
  ushort8v o;
#pragma unroll
  for (int j = 0; j < 4; ++j) { o[j] = f2bf(f0[j]); o[j + 4] = f2bf(f1[j]); }
  *(ushort8v*)(dst + (size_t)idx * 8) = o;
}

// ---------------- wave-autonomous bf16 MFMA GEMM (no LDS, no barriers) ------
// Block = 4 waves: same 64-row M-tile (A L1-shared), wave w owns 64-col
// N-tile ((j%NB)*4+w)*64. Both operands fragment-ordered: every load is
// base + lane*16B (coalesced, register-direct). XCD-pinned M rows.
// EPI 0: f32x4 transpose-write vxt[(b*768+n)*196+np]
// EPI 1: f32 C[m*Nr+n] = acc + bias[n] + res[m*Nr+n]
// EPI 2: bf16 gelu(acc+bias[n]) written in FRAGMENT order (as fc2's A)
template<int EPI>
__global__ __launch_bounds__(256) void gemmw_k(
    const u16* __restrict__ Af, const u16* __restrict__ Bf,
    const float* __restrict__ bias, const float* __restrict__ res,
    void* __restrict__ Cp, int Nr, int Kr, int NB) {
  const int t = threadIdx.x, w = t >> 6, lane = t & 63;
  const int bid = blockIdx.x;
  const int xcd = bid & 7, j = bid >> 3;
  const int mt = xcd + 8 * (j / NB);
  if (mt >= 98) return;
  const int m0 = mt * 64;
  const int n0 = ((j % NB) * 4 + w) * 64;
  const int KC = Kr >> 5;
  const int l15 = lane & 15, l4 = lane >> 4;

  const u16* Ab = Af + ((size_t)(m0 >> 4) * KC) * 512 + lane * 8;
  const u16* Bb = Bf + ((size_t)(n0 >> 4) * KC) * 512 + lane * 8;

  f32x4 acc[4][4];
#pragma unroll
  for (int a = 0; a < 4; ++a)
#pragma unroll
    for (int b2 = 0; b2 < 4; ++b2) acc[a][b2] = (f32x4){0.f, 0.f, 0.f, 0.f};

  for (int kc = 0; kc < KC; ++kc) {
    bf16x8 af[4], bfv[4];
#pragma unroll
    for (int mb = 0; mb < 4; ++mb)
      af[mb] = *(const bf16x8*)(Ab + ((size_t)mb * KC + kc) * 512);
#pragma unroll
    for (int nb = 0; nb < 4; ++nb)
      bfv[nb] = *(const bf16x8*)(Bb + ((size_t)nb * KC + kc) * 512);
#pragma unroll
    for (int mb = 0; mb < 4; ++mb)
#pragma unroll
      for (int nb = 0; nb < 4; ++nb)
        acc[mb][nb] = __builtin_amdgcn_mfma_f32_16x16x32_bf16(af[mb], bfv[nb], acc[mb][nb], 0, 0, 0);
  }

#pragma unroll
  for (int mb = 0; mb < 4; ++mb) {
#pragma unroll
    for (int nb = 0; nb < 4; ++nb) {
      int n = n0 + nb * 16 + l15;
      if (EPI == 0) {
        int m0r = m0 + mb * 16 + l4 * 4;
        int bb = m0r / 196, np0 = m0r - bb * 196;   // 4-aligned, same bb r=0..3
        *(float4v*)&((float*)Cp)[((size_t)bb * DIMC + n) * 196 + np0] =
            (float4v){acc[mb][nb][0], acc[mb][nb][1], acc[mb][nb][2], acc[mb][nb][3]};
      } else {
#pragma unroll
        for (int r = 0; r < 4; ++r) {
          int m = m0 + mb * 16 + l4 * 4 + r;
          float v = acc[mb][nb][r];
          if (EPI == 1) {
            ((float*)Cp)[(size_t)m * Nr + n] = v + bias[n] + res[(size_t)m * Nr + n];
          } else {
            float vb = v + bias[n];
            float ge = 0.5f * vb * (1.f + erff(vb * 0.70710678118654752f));
            ((u16*)Cp)[fidx(m, n, Nr)] = f2bf(ge);
          }
        }
      }
    }
  }
}

// ---------------- MFMA screen: max_i max_p |u_i| per tile, flag > 3.4 ----------
__global__ __launch_bounds__(64) void checkmfma_k(
    const float* __restrict__ vxt, const float* __restrict__ kern,
    const u16* __restrict__ Ff, const u16* __restrict__ Gf,
    int* __restrict__ cnt, int* __restrict__ wl) {
  __shared__ float xf[16 * 228];
  const int lane = threadIdx.x;
  const int wgb = blockIdx.x;
  const int g = wgb >> 1, bhalf = wgb & 1;
  const int tl = lane & 15, h = lane >> 4;
  const float* xbase = vxt + ((size_t)(bhalf * 16 + tl) * DIMC + g) * 196;

  bf16x8 Bx[7];
#pragma unroll
  for (int k0 = 0; k0 < 7; ++k0) {
    int q0 = k0 * 32 + h * 8;
    ushort8v tv;
    if (k0 < 6) {
      float4v f0 = *(const float4v*)(xbase + q0);
      float4v f1 = *(const float4v*)(xbase + q0 + 4);
#pragma unroll
      for (int j = 0; j < 4; ++j) { tv[j] = f2bf(f0[j]); tv[j + 4] = f2bf(f1[j]); }
    } else {
#pragma unroll
      for (int j = 0; j < 8; ++j) {
        int q = q0 + j;
        tv[j] = (q < 196) ? f2bf(xbase[q]) : (u16)0;
      }
    }
    Bx[k0] = __builtin_bit_cast(bf16x8, tv);
  }

  for (int m0 = 0; m0 < 14; ++m0) {
    f32x4 acc = (f32x4){0.f, 0.f, 0.f, 0.f};
#pragma unroll
    for (int k0 = 0; k0 < 7; ++k0) {
      bf16x8 Af = __builtin_bit_cast(bf16x8,
          *(const ushort8v*)(Ff + ((size_t)(m0 * 7 + k0) * 64 + lane) * 8));
      acc = __builtin_amdgcn_mfma_f32_16x16x32_bf16(Af, Bx[k0], acc, 0, 0, 0);
    }
    *(f32x4*)&xf[tl * 228 + m0 * 16 + h * 4] = acc;
  }

  bf16x8 By[5][7];
#pragma unroll
  for (int i = 0; i < 5; ++i) {
    const float* kb = kern + ((size_t)g * 5 + i) * 224;
#pragma unroll
    for (int k0 = 0; k0 < 7; ++k0) {
      f32x4 x0 = *(const f32x4*)&xf[tl * 228 + k0 * 32 + h * 8];
      f32x4 x1 = *(const f32x4*)&xf[tl * 228 + k0 * 32 + h * 8 + 4];
      int mb = k0 * 16 + h * 4;
      float2 ka = *(const float2*)(kb + (mb + 0) * 2);
      float2 kc = *(const float2*)(kb + (mb + 1) * 2);
      float2 ke = *(const float2*)(kb + (mb + 2) * 2);
      float2 kg = *(const float2*)(kb + (mb + 3) * 2);
      ushort8v tv;
      tv[0] = f2bf(ka.x * x0[0] - ka.y * x0[1]);
      tv[1] = f2bf(ka.x * x0[1] + ka.y * x0[0]);
      tv[2] = f2bf(kc.x * x0[2] - kc.y * x0[3]);
      tv[3] = f2bf(kc.x * x0[3] + kc.y * x0[2]);
      tv[4] = f2bf(ke.x * x1[0] - ke.y * x1[1]);
      tv[5] = f2bf(ke.x * x1[1] + ke.y * x1[0]);
      tv[6] = f2bf(kg.x * x1[2] - kg.y * x1[3]);
      tv[7] = f2bf(kg.x * x1[3] + kg.y * x1[2]);
      By[i][k0] = __builtin_bit_cast(bf16x8, tv);
    }
  }

  float vmax = 0.f;
  for (int p0 = 0; p0 < 13; ++p0) {
    f32x4 a0 = (f32x4){0.f, 0.f, 0.f, 0.f};
    f32x4 a1 = a0, a2 = a0, a3 = a0, a4 = a0;
#pragma unroll
    for (int k0 = 0; k0 < 7; ++k0) {
      bf16x8 Ag = __builtin_bit_cast(bf16x8,
          *(const ushort8v*)(Gf + ((size_t)(p0 * 7 + k0) * 64 + lane) * 8));
      a0 = __builtin_amdgcn_mfma_f32_16x16x32_bf16(Ag, By[0][k0], a0, 0, 0, 0);
      a1 = __builtin_amdgcn_mfma_f32_16x16x32_bf16(Ag, By[1][k0], a1, 0, 0, 0);
      a2 = __builtin_amdgcn_mfma_f32_16x16x32_bf16(Ag, By[2][k0], a2, 0, 0, 0);
      a3 = __builtin_amdgcn_mfma_f32_16x16x32_bf16(Ag, By[3][k0], a3, 0, 0, 0);
      a4 = __builtin_amdgcn_mfma_f32_16x16x32_bf16(Ag, By[4][k0], a4, 0, 0, 0);
    }
#pragma unroll
    for (int r = 0; r < 4; ++r) {
      vmax = fmaxf(vmax, fabsf(a0[r]));
      vmax = fmaxf(vmax, fabsf(a1[r]));
      vmax = fmaxf(vmax, fabsf(a2[r]));
      vmax = fmaxf(vmax, fabsf(a3[r]));
      vmax = fmaxf(vmax, fabsf(a4[r]));
    }
  }
  vmax = fmaxf(vmax, __shfl_xor(vmax, 16));
  vmax = fmaxf(vmax, __shfl_xor(vmax, 32));
  if (lane < 16 && vmax > (LAMC - 0.1f)) {
    int idx = atomicAdd(cnt, 1);
    wl[idx] = g * 32 + bhalf * 16 + lane;
  }
}

// ---------------- full ISTA for flagged tiles + fused tile sums -------------
__global__ __launch_bounds__(64) void slow_k(
    const float* __restrict__ vxt, const float* __restrict__ kern,
    const float* __restrict__ kern2, const float* __restrict__ Lbuf,
    const int* __restrict__ cnt, const int* __restrict__ wl,
    float* __restrict__ outp,
    float* __restrict__ tsum, float* __restrict__ tsq,
    unsigned* __restrict__ maskg, unsigned* __restrict__ bmask) {
  const int ntile = *cnt;
  if ((int)blockIdx.x >= ntile) return;
  const int t = threadIdx.x;
  __shared__ float TC[196], TSn[196];
  __shared__ float xs[196];
  __shared__ float t1R[112], t1I[112];
  __shared__ float t2R[112], t2I[112];
  __shared__ float zr[112], zi[112];
  __shared__ float kR[5][112], kI[5][112];
  __shared__ float uu[5][196];
  __shared__ float ss[5][196];
  __shared__ float k2R[112], k2I[112];

  for (int i = t; i < 196; i += 64) {
    int a = i / 14, c = i - (i / 14) * 14;
    int m = (a * c) % 14;
    TC[i] = C14d[m]; TSn[i] = S14d[m];
  }

  auto rowsFwd = [&](const float* xsrc) {
    for (int i = t; i < 112; i += 64) {
      int r = i >> 3, f = i & 7;
      const float* xp = xsrc + r * 14;
      const float* tc = &TC[f * 14]; const float* tsn = &TSn[f * 14];
      float ar = 0.f, ai = 0.f;
#pragma unroll
      for (int c = 0; c < 14; ++c) { float xv = xp[c]; ar += xv * tc[c]; ai -= xv * tsn[c]; }
      t1R[i] = ar; t1I[i] = ai;
    }
    __syncthreads();
  };
  auto colsFwd = [&](float* oR, float* oI) {
    for (int i = t; i < 112; i += 64) {
      int kr = i >> 3, f = i & 7;
      const float* tc = &TC[kr * 14]; const float* tsn = &TSn[kr * 14];
      float br = 0.f, bi = 0.f;
#pragma unroll
      for (int r = 0; r < 14; ++r) {
        float xr = t1R[r * 8 + f], xi = t1I[r * 8 + f];
        br += tc[r] * xr + tsn[r] * xi;
        bi += tc[r] * xi - tsn[r] * xr;
      }
      oR[i] = br; oI[i] = bi;
    }
    __syncthreads();
  };
  auto colsInv = [&]() {
    for (int i = t; i < 112; i += 64) {
      int r = i >> 3, f = i & 7;
      const float* tc = &TC[r * 14]; const float* tsn = &TSn[r * 14];
      float br = 0.f, bi = 0.f;
#pragma unroll
      for (int kr = 0; kr < 14; ++kr) {
        float xr = t1R[kr * 8 + f], xi = t1I[kr * 8 + f];
        br += tc[kr] * xr - tsn[kr] * xi;
        bi += tc[kr] * xi + tsn[kr] * xr;
      }
      t2R[i] = br; t2I[i] = bi;
    }
    __syncthreads();
  };
  auto rowVal = [&](int r, int c) -> float {
    const float* pR = &t2R[r * 8]; const float* pI = &t2I[r * 8];
    float v = pR[0] + ((c & 1) ? -pR[7] : pR[7]);
    float s2 = 0.f;
#pragma unroll
    for (int f = 1; f < 7; ++f) s2 += pR[f] * TC[f * 14 + c] - pI[f] * TSn[f * 14 + c];
    return (v + 2.f * s2) * (1.0f / 196.0f);
  };

  for (int widx = blockIdx.x; widx < ntile; widx += gridDim.x) {
    const int tile = wl[widx];
    const int g = tile >> 5, b = tile & 31;
    __syncthreads();
    for (int i = t; i < 560; i += 64) {
      int ii = i / 112, p = i - ii * 112;
      const float* kp = kern + ((size_t)g * 5 + ii) * 224 + p * 2;
      kR[ii][p] = kp[0]; kI[ii][p] = kp[1];
    }
    for (int i = t; i < 196; i += 64) xs[i] = vxt[((size_t)b * DIMC + g) * 196 + i];
    for (int i = t; i < 112; i += 64) {
      k2R[i] = kern2[(size_t)g * 224 + i * 2];
      k2I[i] = kern2[(size_t)g * 224 + i * 2 + 1];
    }
    __syncthreads();

    rowsFwd(xs);
    colsFwd(zr, zi);
    for (int ii = 0; ii < 5; ++ii) {
      for (int i = t; i < 112; i += 64) {
        float a = kR[ii][i], b2 = kI[ii][i];
        t1R[i] = a * zr[i] - b2 * zi[i];
        t1I[i] = a * zi[i] + b2 * zr[i];
      }
      __syncthreads();
      colsInv();
      for (int i = t; i < 196; i += 64) uu[ii][i] = rowVal(i / 14, i - (i / 14) * 14);
      __syncthreads();
    }

    const float invL = 1.0f / Lbuf[g];
    const float thr = LAMC * invL;
    {
      float* up = &uu[0][0];
      float* sp = &ss[0][0];
      for (int i = t; i < 980; i += 64) {
        float v = up[i];
        float a = fabsf(v) - LAMC;
        sp[i] = a > 0.f ? copysignf(a, v) : 0.f;
      }
    }
    __syncthreads();

    for (int iter = 0; iter < 4; ++iter) {
      for (int i = t; i < 112; i += 64) { zr[i] = 0.f; zi[i] = 0.f; }
      __syncthreads();
      for (int ii = 0; ii < 5; ++ii) {
        rowsFwd(&ss[ii][0]);
        colsFwd(t2R, t2I);
        for (int i = t; i < 112; i += 64) {
          float a = kR[ii][i], b2 = kI[ii][i];
          zr[i] += a * t2R[i] + b2 * t2I[i];
          zi[i] += a * t2I[i] - b2 * t2R[i];
        }
        __syncthreads();
      }
      if (iter == 3) break;
      for (int ii = 0; ii < 5; ++ii) {
        for (int i = t; i < 112; i += 64) {
          float a = kR[ii][i], b2 = kI[ii][i];
          t1R[i] = a * zr[i] - b2 * zi[i];
          t1I[i] = a * zi[i] + b2 * zr[i];
        }
        __syncthreads();
        colsInv();
        for (int i = t; i < 196; i += 64) {
          float v = rowVal(i / 14, i - (i / 14) * 14);
          float sv = ss[ii][i] - (v - uu[ii][i]) * invL;
          float aa = fabsf(sv) - thr;
          ss[ii][i] = aa > 0.f ? copysignf(aa, sv) : 0.f;
        }
        __syncthreads();
      }
    }

    if (t < 28) {
      int kr = t >> 1, f = (t & 1) * 7;
      int d = kr * 8 + f;
      int srci = ((14 - kr) % 14) * 8 + f;
      float pr = 0.5f * (zr[d] + zr[srci]);
      float pi = 0.5f * (zi[d] - zi[srci]);
      zr[d] = pr; zi[d] = pi;
    }
    __syncthreads();
    for (int i = t; i < 112; i += 64) {
      float a = k2R[i], b2 = k2I[i];
      t1R[i] = a * zr[i] - b2 * zi[i];
      t1I[i] = a * zi[i] + b2 * zr[i];
    }
    __syncthreads();
    colsInv();
    float sacc = 0.f, qacc = 0.f;
    for (int i = t; i < 196; i += 64) {
      float v = rowVal(i / 14, i - (i / 14) * 14);
      outp[((size_t)(b * 196 + i)) * DIMC + g] = v;
      sacc += v; qacc += v * v;
    }
#pragma unroll
    for (int off = 32; off; off >>= 1) {
      sacc += __shfl_xor(sacc, off);
      qacc += __shfl_xor(qacc, off);
    }
    if (t == 0) {
      tsum[tile] = sacc; tsq[tile] = qacc;
      atomicOr(&maskg[g], 1u << b);
      atomicOr(bmask, 1u << b);
    }
  }
}

// ---------------- BN1 finalize + c0 in one dispatch (3 blocks) --------------
__global__ __launch_bounds__(256) void stats1c0_k(
    const float* __restrict__ tsum, const float* __restrict__ tsq,
    const unsigned* __restrict__ maskg,
    const float* __restrict__ gam, const float* __restrict__ bet,
    const float* __restrict__ projw, const float* __restrict__ pb,
    float* __restrict__ sc1, float* __restrict__ c0) {
  __shared__ float sh1s[768];
  const int t = threadIdx.x;
  for (int c = t; c < DIMC; c += 256) {
    unsigned mask = maskg[c];
    float S = 0.f, Q = 0.f;
    if (mask) {
      for (int b = 0; b < 32; ++b)
        if ((mask >> b) & 1) { S += tsum[c * 32 + b]; Q += tsq[c * 32 + b]; }
    }
    float m = S * (1.0f / 6272.0f);
    float v = fmaxf(Q * (1.0f / 6272.0f) - m * m, 0.f);
    float rs = rsqrtf(v + 1e-5f);
    float sc = gam[c] * rs;
    sh1s[c] = bet[c] - m * sc;
    if (blockIdx.x == 0) sc1[c] = sc;
  }
  __syncthreads();
  int n = blockIdx.x * 256 + t;
  const float* row = projw + (size_t)n * DIMC;
  float s = 0.f;
  for (int g = 0; g < DIMC; g += 4) {
    float4v r = *(const float4v*)(row + g);
    s += r[0] * sh1s[g] + r[1] * sh1s[g + 1] + r[2] * sh1s[g + 2] + r[3] * sh1s[g + 3];
  }
  c0[n] = s + pb[n];
}

// ---------------- fused: new2 = x + c0 + sparse-corr; f32 + frag-bf16; BN2 partials
__global__ __launch_bounds__(256) void bnb_k(
    const float* __restrict__ x, const float* __restrict__ c0,
    const float* __restrict__ sc1, const unsigned* __restrict__ maskg,
    const unsigned* __restrict__ bmask, const float* __restrict__ newm,
    const float* __restrict__ projw,
    float* __restrict__ new2, u16* __restrict__ n2f,
    float* __restrict__ part) {
  const int jb = blockIdx.x, b = blockIdx.y, t = threadIdx.x;
  __shared__ unsigned gm[24];
  __shared__ float c0s[768];
  const bool hasb = ((*bmask >> b) & 1u) != 0u;
  if (t < 24) {
    unsigned w = 0;
    if (hasb)
      for (int j2 = 0; j2 < 32; ++j2) w |= ((maskg[t * 32 + j2] >> b) & 1u) << j2;
    gm[t] = w;
  }
  for (int c = t; c < 768; c += 256) c0s[c] = c0[c];
  __syncthreads();

  float S0 = 0, S1 = 0, S2 = 0, Q0 = 0, Q1 = 0, Q2 = 0;
  for (int mr = 0; mr < 7; ++mr) {
    int m = b * 196 + jb * 7 + mr;
    size_t row = (size_t)m * DIMC;
#pragma unroll
    for (int j2 = 0; j2 < 3; ++j2) {
      int n = t + j2 * 256;
      float v = x[row + n] + c0s[n];
      if (hasb) {
        for (int w = 0; w < 24; ++w) {
          unsigned bits = gm[w];
          while (bits) {
            int g = w * 32 + __builtin_ctz(bits);
            bits &= bits - 1;
            v += sc1[g] * newm[row + g] * projw[(size_t)n * DIMC + g];
          }
        }
      }
      new2[row + n] = v;
      n2f[fidx(m, n, DIMC)] = f2bf(v);
      if (j2 == 0) { S0 += v; Q0 += v * v; }
      else if (j2 == 1) { S1 += v; Q1 += v * v; }
      else { S2 += v; Q2 += v * v; }
    }
  }
  float* p = part + (size_t)(b * 28 + jb) * 1536;
  p[t] = S0; p[t + 256] = S1; p[t + 512] = S2;
  p[768 + t] = Q0; p[768 + 256 + t] = Q1; p[768 + 512 + t] = Q2;
}

// ---------------- BN2 reduce stage A (collapse jb) ---------------------------
__global__ __launch_bounds__(256) void red2_k(const float* __restrict__ part,
                                              float* __restrict__ part2) {
  int slot = blockIdx.x * 256 + threadIdx.x;   // 0..1535
  int b = blockIdx.y;
  float s = 0.f;
  const float* p = part + (size_t)(b * 28) * 1536 + slot;
  for (int jb = 0; jb < 28; ++jb) s += p[(size_t)jb * 1536];
  part2[(size_t)b * 1536 + slot] = s;
}

// ---------------- BN2 finalize ----------------------------------------------
__global__ __launch_bounds__(256) void stats2fin_k(const float* __restrict__ part2,
    const float* __restrict__ gam, const float* __restrict__ bet,
    float* __restrict__ scale, float* __restrict__ shift) {
  int c = blockIdx.x * 256 + threadIdx.x;
  float S = 0.f, Q = 0.f;
  for (int b = 0; b < 32; ++b) {
    S += part2[(size_t)b * 1536 + c];
    Q += part2[(size_t)b * 1536 + 768 + c];
  }
  float m = S * (1.0f / 6272.0f);
  float v = fmaxf(Q * (1.0f / 6272.0f) - m * m, 0.f);
  float rs = rsqrtf(v + 1e-5f);
  float sc = gam[c] * rs;
  scale[c] = sc;
  shift[c] = bet[c] - m * sc;
}

// ---------------- fold BN2 into fc1: d0 + frag-pack fc1s --------------------
__global__ __launch_bounds__(256) void foldfc1_k(const float* __restrict__ fc1w,
    const float* __restrict__ fc1b, const float* __restrict__ sc2,
    const float* __restrict__ sh2, u16* __restrict__ fc1s,
    float* __restrict__ d0) {
  const int bid = blockIdx.x, t = threadIdx.x;
  if (bid < 12) {
    int n = bid * 256 + t;
    const float* row = fc1w + (size_t)n * DIMC;
    float s = 0.f;
    for (int k = 0; k < DIMC; k += 4) {
      float4v r = *(const float4v*)(row + k);
      float4v h = *(const float4v*)(sh2 + k);
      s += r[0] * h[0] + r[1] * h[1] + r[2] * h[2] + r[3] * h[3];
    }
    d0[n] = s + fc1b[n];
  } else {
    int idx = (bid - 12) * 256 + t;          // 294912 threads: frag-pack
    int chunk = idx >> 6, l = idx & 63;
    int n = (chunk / 24) * 16 + (l & 15);
    int k0 = (chunk % 24) * 32 + (l >> 4) * 8;
    const float* sp = fc1w + (size_t)n * DIMC + k0;
    float4v f0 = *(const float4v*)sp;
    float4v f1 = *(const float4v*)(sp + 4);
    float4v s0 = *(const float4v*)(sc2 + k0);
    float4v s1 = *(const float4v*)(sc2 + k0 + 4);
    f0 = f0 * s0; f1 = f1 * s1;
    ushort8v o;
#pragma unroll
    for (int j = 0; j < 4; ++j) { o[j] = f2bf(f0[j]); o[j + 4] = f2bf(f1[j]); }
    *(ushort8v*)(fc1s + (size_t)idx * 8) = o;
  }
}

// ---------------- launch ----------------
extern "C" void kernel_launch(void* const* d_in, const int* in_sizes, int n_in,
                              void* d_out, int out_size, void* d_ws, size_t ws_size,
                              hipStream_t stream) {
  (void)in_sizes; (void)n_in; (void)out_size;
  const float* x      = (const float*)d_in[0];
  const float* v_w    = (const float*)d_in[1];
  const float* proj_w = (const float*)d_in[2];
  const float* proj_b = (const float*)d_in[3];
  const float* kern   = (const float*)d_in[4];
  const float* kern2  = (const float*)d_in[5];
  const float* n1g    = (const float*)d_in[6];
  const float* n1b    = (const float*)d_in[7];
  const float* n2g    = (const float*)d_in[8];
  const float* n2b    = (const float*)d_in[9];
  const float* fc1w   = (const float*)d_in[10];
  const float* fc1b   = (const float*)d_in[11];
  const float* fc2w   = (const float*)d_in[12];
  const float* fc2b   = (const float*)d_in[13];
  const float* Lb     = (const float*)d_in[14];
  float* out = (float*)d_out;

  char* ws = (char*)d_ws;
  size_t o = 0;
  auto alloc = [&](size_t bytes) { size_t r = o; o += (bytes + 255) & ~(size_t)255; return r; };
  u16*   vwf    = (u16*)(ws + alloc(589824 * 2));
  u16*   fc2f   = (u16*)(ws + alloc(2359296 * 2));
  u16*   fc1s   = (u16*)(ws + alloc(2359296 * 2));
  u16*   Ffb    = (u16*)(ws + alloc(50176 * 2));
  u16*   Gfb    = (u16*)(ws + alloc(46592 * 2));
  float* sc1    = (float*)(ws + alloc(768 * 4));
  float* sc2    = (float*)(ws + alloc(768 * 4));
  float* sh2    = (float*)(ws + alloc(768 * 4));
  float* c0     = (float*)(ws + alloc(768 * 4));
  float* d0     = (float*)(ws + alloc(3072 * 4));
  float* part   = (float*)(ws + alloc((size_t)896 * 1536 * 4));
  float* part2  = (float*)(ws + alloc((size_t)32 * 1536 * 4));
  char*  zblk   = (char*)(ws + alloc(4096));       // cnt(4) | bmask(4) | maskg(3072)
  int*      cnt   = (int*)zblk;
  unsigned* bmask = (unsigned*)(zblk + 4);
  unsigned* maskg = (unsigned*)(zblk + 8);
  int*   wl     = (int*)(ws + alloc(24576 * 4));
  float* tsum   = (float*)(ws + alloc(24576 * 4));
  float* tsq    = (float*)(ws + alloc(24576 * 4));
  u16*   xf     = (u16*)(ws + alloc((size_t)MTOT * DIMC * 2));
  u16*   n2f    = (u16*)(ws + alloc((size_t)MTOT * DIMC * 2));
  float* vxt    = (float*)(ws + alloc((size_t)MTOT * DIMC * 4));
  float* newm   = (float*)(ws + alloc((size_t)MTOT * DIMC * 4));
  float* new2   = (float*)(ws + alloc((size_t)MTOT * DIMC * 4));
  u16*   hbf    = (u16*)vxt;   // overlay: h frag (38.5 MB) over vxt+newm (dead by fc1)
  if (ws_size < o) return;

  hipMemsetAsync(zblk, 0, 4096, stream);

  // prep: DFT frag matrices + frag-pack v_w, fc2w, x
  prep_k<<<4170, 256, 0, stream>>>(v_w, fc2w, x, vwf, fc2f, xf, Ffb, Gfb);
  // vx = x @ v_w^T, transpose-written as (b, g, n)   grid 8*3*13
  gemmw_k<0><<<312, 256, 0, stream>>>(xf, vwf, nullptr, nullptr, vxt, DIMC, DIMC, 3);
  // MFMA screen -> worklist
  checkmfma_k<<<1536, 64, 0, stream>>>(vxt, kern, Ffb, Gfb, cnt, wl);
  // exact ISTA for flagged tiles + per-tile BN1 sums + masks
  slow_k<<<1024, 64, 0, stream>>>(vxt, kern, kern2, Lb, cnt, wl, newm,
                                  tsum, tsq, maskg, bmask);
  // BN1 finalize + c0 = projW @ sh1 + proj_b
  stats1c0_k<<<3, 256, 0, stream>>>(tsum, tsq, maskg, n1g, n1b, proj_w, proj_b, sc1, c0);
  // new2 = x + c0 + sparse corr; f32 + frag bf16; BN2 partial sums
  bnb_k<<<dim3(28, 32), 256, 0, stream>>>(x, c0, sc1, maskg, bmask, newm, proj_w,
                                          new2, n2f, part);
  // BN2 reduce (two-stage)
  red2_k<<<dim3(6, 32), 256, 0, stream>>>(part, part2);
  stats2fin_k<<<3, 256, 0, stream>>>(part2, n2g, n2b, sc2, sh2);
  // fold BN2 into fc1 (d0 + frag-packed scaled weights)
  foldfc1_k<<<1164, 256, 0, stream>>>(fc1w, fc1b, sc2, sh2, fc1s, d0);
  // h = gelu(new2 @ fc1s^T + d0), written in fc2-A fragment order   grid 8*12*13
  gemmw_k<2><<<1248, 256, 0, stream>>>(n2f, fc1s, d0, nullptr, hbf, HIDC, DIMC, 12);
  // out = new2 + h @ fc2^T + fc2_b   grid 8*3*13
  gemmw_k<1><<<312, 256, 0, stream>>>(hbf, fc2f, fc2b, new2, out, DIMC, HIDC, 3);
}